// Round 6
// baseline (286.691 us; speedup 1.0000x reference)
//
#include <hip/hip_runtime.h>
#include <math.h>

#define N_NODES 50000
#define N_EDGES 800000
#define NUM_GRAPHS 512
#define NEG_SLOPE 0.2f
#define LOG_MD 6
#define MAXDEG 63          // slots 0..62 hold neighbors (self at 0); slot 63 = counter

// ---------------- padded-CSR build, counter colocated in the row ----------------
// col row for node d: [self, e1, e2, ..., counter@63]. Counter starts at 1.
__global__ void init_col_k(int* __restrict__ col) {
    int i = blockIdx.x * blockDim.x + threadIdx.x;
    if (i < N_NODES) {
        col[((size_t)i << LOG_MD) + 0]  = i;   // self loop
        col[((size_t)i << LOG_MD) + 63] = 1;   // count (includes self)
    }
}

// 4 independent edges per thread; atomic + store hit the same 256B row.
__global__ void scatter4_k(const int* __restrict__ ei, int* __restrict__ col) {
    const int NT = N_EDGES / 4;
    int t = blockIdx.x * blockDim.x + threadIdx.x;
    if (t >= NT) return;
    int4 s4 = ((const int4*)ei)[t];
    int4 d4 = ((const int4*)(ei + N_EDGES))[t];
    int c0 = atomicAdd(col + ((size_t)d4.x << LOG_MD) + 63, 1);
    int c1 = atomicAdd(col + ((size_t)d4.y << LOG_MD) + 63, 1);
    int c2 = atomicAdd(col + ((size_t)d4.z << LOG_MD) + 63, 1);
    int c3 = atomicAdd(col + ((size_t)d4.w << LOG_MD) + 63, 1);
    if (c0 < MAXDEG) col[((size_t)d4.x << LOG_MD) + c0] = s4.x;
    if (c1 < MAXDEG) col[((size_t)d4.y << LOG_MD) + c1] = s4.y;
    if (c2 < MAXDEG) col[((size_t)d4.z << LOG_MD) + c2] = s4.z;
    if (c3 < MAXDEG) col[((size_t)d4.w << LOG_MD) + c3] = s4.w;
}

// ---------------- tiled node linear (xl = xW_l + bl, xr = xW_r) ----------------
template<int FIN, int FOUT, int NPB>
__global__ void __launch_bounds__(256) node_linear2_k(
        const float* __restrict__ x,
        const float* __restrict__ Wl, const float* __restrict__ bl,
        const float* __restrict__ Wr,
        float* __restrict__ xl, float* __restrict__ xr) {
    const int GROUPS = 256 / FOUT;
    const int NPG = NPB / GROUPS;   // nodes per thread
    __shared__ float xs[NPB * FIN];
    const int tid = threadIdx.x;
    const int n0_blk = blockIdx.x * NPB;
    const int nodes_here = min(NPB, N_NODES - n0_blk);

    const float4* xv = (const float4*)(x + (size_t)n0_blk * FIN);
    const int total4 = nodes_here * FIN / 4;
    for (int i = tid; i < total4; i += 256) ((float4*)xs)[i] = xv[i];
    __syncthreads();

    const int j = tid % FOUT;
    const int g = tid / FOUT;
    float al[NPG], ar[NPG];
    const float blj = bl[j];
    #pragma unroll
    for (int i = 0; i < NPG; ++i) { al[i] = blj; ar[i] = 0.f; }

    const float* xbase = xs + (size_t)g * NPG * FIN;
    for (int k = 0; k < FIN; k += 4) {
        float wl0 = Wl[(k + 0) * FOUT + j], wl1 = Wl[(k + 1) * FOUT + j];
        float wl2 = Wl[(k + 2) * FOUT + j], wl3 = Wl[(k + 3) * FOUT + j];
        float wr0 = Wr[(k + 0) * FOUT + j], wr1 = Wr[(k + 1) * FOUT + j];
        float wr2 = Wr[(k + 2) * FOUT + j], wr3 = Wr[(k + 3) * FOUT + j];
        #pragma unroll
        for (int i = 0; i < NPG; ++i) {
            float4 v = *(const float4*)(xbase + i * FIN + k);   // wave-uniform broadcast
            al[i] = fmaf(v.x, wl0, fmaf(v.y, wl1, fmaf(v.z, wl2, fmaf(v.w, wl3, al[i]))));
            ar[i] = fmaf(v.x, wr0, fmaf(v.y, wr1, fmaf(v.z, wr2, fmaf(v.w, wr3, ar[i]))));
        }
    }
    const int nbase = n0_blk + g * NPG;
    #pragma unroll
    for (int i = 0; i < NPG; ++i) {
        int n = nbase + i;
        if (n < N_NODES) {
            xl[(size_t)n * FOUT + j] = al[i];
            xr[(size_t)n * FOUT + j] = ar[i];
        }
    }
}

// ---------------- fused GATv2 conv, float4 channels, padded CSR ----------------
// lane -> (node slot, float4 channel group). LPN lanes/node, NPW = 64/LPN nodes
// per wave. Row base = n<<LOG_MD; degree = col[base+63] (capped at 63).
// Softmax shift-invariance: skip max subtraction, clamp score at 80.
template<int C2, int LPN, int HEADL>   // channels, lanes/node = C2/4, lanes/head = LPN/2
__global__ void gat_conv_k(const int* __restrict__ col,
                           const float4* __restrict__ xl4, const float4* __restrict__ xr4,
                           const float* __restrict__ att, const float* __restrict__ b,
                           float* __restrict__ out) {
    const int NPW = 64 / LPN;
    const int V4  = C2 / 4;      // float4s per node row (== LPN)
    int wave = (blockIdx.x * blockDim.x + threadIdx.x) >> 6;
    int lane = threadIdx.x & 63;
    int slot = lane / LPN;
    int c4   = lane % LPN;
    int n = wave * NPW + slot;
    const bool nvalid = (n < N_NODES);
    const int nn = nvalid ? n : (N_NODES - 1);

    const float4 xr_c  = xr4[(size_t)nn * V4 + c4];
    const float4 att_c = ((const float4*)att)[c4];
    const float4 b_c   = ((const float4*)b)[c4];

    const int start = nn << LOG_MD;
    const int dg    = nvalid ? min(col[start + 63], MAXDEG) : 0;

    // wave-wide max degree (all lanes active; loop is wave-uniform)
    int mdg = dg;
    #pragma unroll
    for (int off = 32; off > 0; off >>= 1) mdg = max(mdg, __shfl_xor(mdg, off, 64));

    float den = 0.f;
    float4 acc = {0.f, 0.f, 0.f, 0.f};
    float4 cur = xl4[(size_t)col[start] * V4 + c4];   // deg >= 1 always (self loop)
    for (int k = 0; k < mdg; ++k) {
        float4 x4 = cur;
        if (k + 1 < mdg) {
            int kk = min(k + 1, dg - 1);
            if (kk < 0) kk = 0;
            int sn = col[start + kk];
            cur = xl4[(size_t)sn * V4 + c4];          // in flight during math below
        }
        float z0 = x4.x + xr_c.x; z0 = (z0 >= 0.f) ? z0 : NEG_SLOPE * z0;
        float z1 = x4.y + xr_c.y; z1 = (z1 >= 0.f) ? z1 : NEG_SLOPE * z1;
        float z2 = x4.z + xr_c.z; z2 = (z2 >= 0.f) ? z2 : NEG_SLOPE * z2;
        float z3 = x4.w + xr_c.w; z3 = (z3 >= 0.f) ? z3 : NEG_SLOPE * z3;
        float p = fmaf(z0, att_c.x, fmaf(z1, att_c.y, fmaf(z2, att_c.z, z3 * att_c.w)));
        #pragma unroll
        for (int off = HEADL / 2; off > 0; off >>= 1)
            p += __shfl_xor(p, off, 64);
        float ex = (k < dg) ? __expf(fminf(p, 80.f)) : 0.f;
        den += ex;
        acc.x = fmaf(ex, x4.x, acc.x);
        acc.y = fmaf(ex, x4.y, acc.y);
        acc.z = fmaf(ex, x4.z, acc.z);
        acc.w = fmaf(ex, x4.w, acc.w);
    }
    if (nvalid) {
        float inv = 1.f / den;
        float4 o;
        o.x = fmaf(acc.x, inv, b_c.x); o.x = (o.x > 0.f) ? o.x : (__expf(o.x) - 1.f);
        o.y = fmaf(acc.y, inv, b_c.y); o.y = (o.y > 0.f) ? o.y : (__expf(o.y) - 1.f);
        o.z = fmaf(acc.z, inv, b_c.z); o.z = (o.z > 0.f) ? o.z : (__expf(o.z) - 1.f);
        o.w = fmaf(acc.w, inv, b_c.w); o.w = (o.w > 0.f) ? o.w : (__expf(o.w) - 1.f);
        ((float4*)out)[(size_t)n * V4 + c4] = o;
    }
}

// ---------------- pool + head ----------------
// batch is sorted: accumulate runs locally, one atomic per run boundary.
__global__ void pool_k(const float* __restrict__ h2, const int* __restrict__ batch,
                       float* __restrict__ gsum, float* __restrict__ gcnt) {
    const int NCH = (N_NODES + 7) / 8;
    int t = blockIdx.x * blockDim.x + threadIdx.x;
    if (t >= NCH * 32) return;
    int c = t & 31;
    int n0 = (t >> 5) * 8;
    int nend = min(n0 + 8, N_NODES);
    int curb = batch[n0];
    float s = 0.f, cnt = 0.f;
    for (int n = n0; n < nend; ++n) {
        int bb = batch[n];
        if (bb != curb) {
            atomicAdd(gsum + (size_t)curb * 32 + c, s);
            if (c == 0) atomicAdd(gcnt + curb, cnt);
            s = 0.f; cnt = 0.f; curb = bb;
        }
        s += h2[(size_t)n * 32 + c];
        cnt += 1.f;
    }
    atomicAdd(gsum + (size_t)curb * 32 + c, s);
    if (c == 0) atomicAdd(gcnt + curb, cnt);
}

__global__ void head_k(const float* __restrict__ gsum, const float* __restrict__ gcnt,
                       const float* __restrict__ Wfc, const float* __restrict__ bfc,
                       float* __restrict__ out) {
    int gph = blockIdx.x * blockDim.x + threadIdx.x;
    if (gph >= NUM_GRAPHS) return;
    float inv = 1.f / fmaxf(gcnt[gph], 1.f);
    float logits[6];
    #pragma unroll
    for (int j = 0; j < 6; ++j) logits[j] = bfc[j];
    for (int k = 0; k < 32; ++k) {
        float p = gsum[(size_t)gph * 32 + k] * inv;
        #pragma unroll
        for (int j = 0; j < 6; ++j) logits[j] = fmaf(p, Wfc[k * 6 + j], logits[j]);
    }
    float m = logits[0];
    #pragma unroll
    for (int j = 1; j < 6; ++j) m = fmaxf(m, logits[j]);
    float ssum = 0.f;
    #pragma unroll
    for (int j = 0; j < 6; ++j) ssum += expf(logits[j] - m);
    float lse = m + logf(ssum);
    #pragma unroll
    for (int j = 0; j < 6; ++j) out[(size_t)gph * 6 + j] = logits[j] - lse;
}

extern "C" void kernel_launch(void* const* d_in, const int* in_sizes, int n_in,
                              void* d_out, int out_size, void* d_ws, size_t ws_size,
                              hipStream_t stream) {
    const float* x    = (const float*)d_in[0];
    const int*   ei   = (const int*)d_in[1];   // [2, N_EDGES]: row0 = src, row1 = dst
    const int*   batch= (const int*)d_in[2];
    const float* Wl1  = (const float*)d_in[3];
    const float* bl1  = (const float*)d_in[4];
    const float* Wr1  = (const float*)d_in[5];
    const float* att1 = (const float*)d_in[6];
    const float* b1   = (const float*)d_in[7];
    const float* Wl2  = (const float*)d_in[8];
    const float* bl2  = (const float*)d_in[9];
    const float* Wr2  = (const float*)d_in[10];
    const float* att2 = (const float*)d_in[11];
    const float* b2   = (const float*)d_in[12];
    const float* Wfc  = (const float*)d_in[13];
    const float* bfc  = (const float*)d_in[14];
    float* out = (float*)d_out;

    // ---- workspace layout ----
    char* wsp = (char*)d_ws;
    float* xl1  = (float*)wsp; wsp += (size_t)N_NODES * 64 * 4;
    float* xr1  = (float*)wsp; wsp += (size_t)N_NODES * 64 * 4;
    float* h1   = (float*)wsp; wsp += (size_t)N_NODES * 64 * 4;
    float* xl2  = (float*)wsp; wsp += (size_t)N_NODES * 32 * 4;
    float* xr2  = (float*)wsp; wsp += (size_t)N_NODES * 32 * 4;
    float* h2   = (float*)wsp; wsp += (size_t)N_NODES * 32 * 4;
    float* gsum = (float*)wsp; wsp += (size_t)NUM_GRAPHS * 32 * 4;
    float* gcnt = (float*)wsp; wsp += (size_t)NUM_GRAPHS * 4;
    int* col    = (int*)wsp; wsp += ((size_t)N_NODES << LOG_MD) * 4;   // 12.8 MB padded CSR

    const int TB = 256;

    // ---- padded-CSR build (counter lives at col[row+63]) ----
    init_col_k<<<(N_NODES + TB - 1) / TB, TB, 0, stream>>>(col);
    scatter4_k<<<(N_EDGES / 4 + TB - 1) / TB, TB, 0, stream>>>(ei, col);

    // ---- layer 1 ----
    node_linear2_k<128, 64, 16><<<(N_NODES + 15) / 16, 256, 0, stream>>>(
        x, Wl1, bl1, Wr1, xl1, xr1);
    {   // 16 lanes/node -> 4 nodes/wave
        int waves = (N_NODES + 3) / 4;
        gat_conv_k<64, 16, 8><<<(waves + 3) / 4, 256, 0, stream>>>(
            col, (const float4*)xl1, (const float4*)xr1, att1, b1, h1);
    }

    // ---- layer 2 ----
    node_linear2_k<64, 32, 32><<<(N_NODES + 31) / 32, 256, 0, stream>>>(
        h1, Wl2, bl2, Wr2, xl2, xr2);
    {   // 8 lanes/node -> 8 nodes/wave
        int waves = (N_NODES + 7) / 8;
        gat_conv_k<32, 8, 4><<<(waves + 3) / 4, 256, 0, stream>>>(
            col, (const float4*)xl2, (const float4*)xr2, att2, b2, h2);
    }

    // ---- pool + head ----
    hipMemsetAsync(gsum, 0, (size_t)(NUM_GRAPHS * 32 + NUM_GRAPHS) * sizeof(float), stream);
    pool_k<<<(((N_NODES + 7) / 8) * 32 + TB - 1) / TB, TB, 0, stream>>>(h2, batch, gsum, gcnt);
    head_k<<<(NUM_GRAPHS + TB - 1) / TB, TB, 0, stream>>>(gsum, gcnt, Wfc, bfc, out);
}

// Round 7
// 274.361 us; speedup vs baseline: 1.0449x; 1.0449x over previous
//
#include <hip/hip_runtime.h>
#include <math.h>

#define N_NODES 50000
#define N_EDGES 800000
#define NUM_GRAPHS 512
#define NEG_SLOPE 0.2f
#define LOG_MD 6
#define ROWCAP 63          // slots 0..62 = real edges; slot 63 = real-edge count
#define NBKT 196           // ceil(50000/256) buckets of 256 dst nodes
#define NPART 200
#define EPB_PART 4000      // NPART * EPB_PART == N_EDGES

// ---------------- stage 1: per-bucket histogram (+ zero gsum/gcnt) ----------------
__global__ void hist_k(const int* __restrict__ ei_dst, int* __restrict__ bucket_cnt,
                       float* __restrict__ gz) {
    __shared__ int h[NBKT];
    const int tid = threadIdx.x;
    for (int i = tid; i < NBKT; i += 256) h[i] = 0;
    int gt = blockIdx.x * 256 + tid;                  // 51200 threads cover 16896
    if (gt < NUM_GRAPHS * 33) gz[gt] = 0.f;           // gsum (512*32) + gcnt (512)
    __syncthreads();
    const int base = blockIdx.x * EPB_PART;
    for (int i = tid; i < EPB_PART; i += 256)
        atomicAdd(&h[ei_dst[base + i] >> 8], 1);
    __syncthreads();
    for (int i = tid; i < NBKT; i += 256)
        if (h[i]) atomicAdd(&bucket_cnt[i], h[i]);
}

// ---------------- stage 2: scan bucket counts ----------------
__global__ void bscan_k(const int* __restrict__ bucket_cnt,
                        int* __restrict__ bucket_off, int* __restrict__ bucket_cur) {
    __shared__ int s[256];
    int tid = threadIdx.x;
    s[tid] = (tid < NBKT) ? bucket_cnt[tid] : 0;
    __syncthreads();
    for (int off = 1; off < 256; off <<= 1) {
        int v = (tid >= off) ? s[tid - off] : 0;
        __syncthreads();
        s[tid] += v;
        __syncthreads();
    }
    if (tid < NBKT) {
        int excl = (tid == 0) ? 0 : s[tid - 1];
        bucket_off[tid] = excl;
        bucket_cur[tid] = excl;
    }
}

// ---------------- stage 3: partition edges into bucket-grouped runs ----------------
__global__ void __launch_bounds__(256) part_k(const int* __restrict__ ei,
                                              int* __restrict__ bucket_cur,
                                              int2* __restrict__ binned) {
    __shared__ int2 ebuf[EPB_PART];   // 32 KB
    __shared__ int2 sbuf[EPB_PART];   // 32 KB
    __shared__ int hist[NBKT], loff[NBKT], rk[NBKT], gbase[NBKT];
    __shared__ int s2[256];
    const int tid = threadIdx.x;
    for (int i = tid; i < NBKT; i += 256) { hist[i] = 0; rk[i] = 0; }
    __syncthreads();
    const int base = blockIdx.x * EPB_PART;
    for (int i = tid; i < EPB_PART; i += 256) {
        int s = ei[base + i];
        int d = ei[N_EDGES + base + i];
        ebuf[i] = make_int2(s, d);
        atomicAdd(&hist[d >> 8], 1);
    }
    __syncthreads();
    // exclusive scan of hist -> loff
    s2[tid] = (tid < NBKT) ? hist[tid] : 0;
    __syncthreads();
    for (int off = 1; off < 256; off <<= 1) {
        int v = (tid >= off) ? s2[tid - off] : 0;
        __syncthreads();
        s2[tid] += v;
        __syncthreads();
    }
    if (tid < NBKT) {
        loff[tid] = (tid == 0) ? 0 : s2[tid - 1];
        gbase[tid] = hist[tid] ? atomicAdd(&bucket_cur[tid], hist[tid]) : 0;
    }
    __syncthreads();
    // reorder into bucket-grouped LDS staging
    for (int i = tid; i < EPB_PART; i += 256) {
        int2 e = ebuf[i];
        int b = e.y >> 8;
        int r = atomicAdd(&rk[b], 1);
        sbuf[loff[b] + r] = e;
    }
    __syncthreads();
    // linear write-out: consecutive threads -> mostly-contiguous global runs
    for (int i = tid; i < EPB_PART; i += 256) {
        int2 e = sbuf[i];
        int b = e.y >> 8;
        binned[gbase[b] + (i - loff[b])] = e;
    }
}

// ---------------- stage 4: build padded CSR rows in LDS, write coalesced ----------------
__global__ void __launch_bounds__(256) build_k(const int* __restrict__ bucket_off,
                                               const int2* __restrict__ binned,
                                               int* __restrict__ col) {
    __shared__ int win[256 * ROWCAP];   // 63 KB
    __shared__ int cnt[256];
    const int tid = threadIdx.x;
    for (int i = tid; i < 256 * ROWCAP; i += 256) win[i] = 0;
    if (tid < 256) cnt[tid] = 0;
    __syncthreads();
    const int b = blockIdx.x;
    const int beg = bucket_off[b];
    const int end = (b == NBKT - 1) ? N_EDGES : bucket_off[b + 1];
    for (int i = beg + tid; i < end; i += 256) {
        int2 e = binned[i];
        int row = e.y & 255;
        int c = atomicAdd(&cnt[row], 1);
        if (c < ROWCAP) win[row * ROWCAP + c] = e.x;
    }
    __syncthreads();
    const int n0 = b << 8;
    const int nrows = min(256, N_NODES - n0);
    int* dst = col + ((size_t)n0 << LOG_MD);
    for (int i = tid; i < nrows * 64; i += 256) {
        int row = i >> 6, s = i & 63;
        dst[i] = (s == 63) ? min(cnt[row], ROWCAP) : win[row * ROWCAP + s];
    }
}

// ---------------- tiled node linear (xl = xW_l + bl, xr = xW_r) ----------------
template<int FIN, int FOUT, int NPB>
__global__ void __launch_bounds__(256) node_linear2_k(
        const float* __restrict__ x,
        const float* __restrict__ Wl, const float* __restrict__ bl,
        const float* __restrict__ Wr,
        float* __restrict__ xl, float* __restrict__ xr) {
    const int GROUPS = 256 / FOUT;
    const int NPG = NPB / GROUPS;   // nodes per thread
    __shared__ float xs[NPB * FIN];
    const int tid = threadIdx.x;
    const int n0_blk = blockIdx.x * NPB;
    const int nodes_here = min(NPB, N_NODES - n0_blk);

    const float4* xv = (const float4*)(x + (size_t)n0_blk * FIN);
    const int total4 = nodes_here * FIN / 4;
    for (int i = tid; i < total4; i += 256) ((float4*)xs)[i] = xv[i];
    __syncthreads();

    const int j = tid % FOUT;
    const int g = tid / FOUT;
    float al[NPG], ar[NPG];
    const float blj = bl[j];
    #pragma unroll
    for (int i = 0; i < NPG; ++i) { al[i] = blj; ar[i] = 0.f; }

    const float* xbase = xs + (size_t)g * NPG * FIN;
    for (int k = 0; k < FIN; k += 4) {
        float wl0 = Wl[(k + 0) * FOUT + j], wl1 = Wl[(k + 1) * FOUT + j];
        float wl2 = Wl[(k + 2) * FOUT + j], wl3 = Wl[(k + 3) * FOUT + j];
        float wr0 = Wr[(k + 0) * FOUT + j], wr1 = Wr[(k + 1) * FOUT + j];
        float wr2 = Wr[(k + 2) * FOUT + j], wr3 = Wr[(k + 3) * FOUT + j];
        #pragma unroll
        for (int i = 0; i < NPG; ++i) {
            float4 v = *(const float4*)(xbase + i * FIN + k);   // wave-uniform broadcast
            al[i] = fmaf(v.x, wl0, fmaf(v.y, wl1, fmaf(v.z, wl2, fmaf(v.w, wl3, al[i]))));
            ar[i] = fmaf(v.x, wr0, fmaf(v.y, wr1, fmaf(v.z, wr2, fmaf(v.w, wr3, ar[i]))));
        }
    }
    const int nbase = n0_blk + g * NPG;
    #pragma unroll
    for (int i = 0; i < NPG; ++i) {
        int n = nbase + i;
        if (n < N_NODES) {
            xl[(size_t)n * FOUT + j] = al[i];
            xr[(size_t)n * FOUT + j] = ar[i];
        }
    }
}

// ---------------- fused GATv2 conv, float4 channels, padded CSR ----------------
// Self loop handled implicitly (xl[n] is a coalesced load); rows hold real
// edges only, count at slot 63. Softmax shift-invariance: no max subtraction.
template<int C2, int LPN, int HEADL>   // channels, lanes/node = C2/4, lanes/head = LPN/2
__global__ void gat_conv_k(const int* __restrict__ col,
                           const float4* __restrict__ xl4, const float4* __restrict__ xr4,
                           const float* __restrict__ att, const float* __restrict__ b,
                           float* __restrict__ out) {
    const int NPW = 64 / LPN;
    const int V4  = C2 / 4;      // float4s per node row (== LPN)
    int wave = (blockIdx.x * blockDim.x + threadIdx.x) >> 6;
    int lane = threadIdx.x & 63;
    int slot = lane / LPN;
    int c4   = lane % LPN;
    int n = wave * NPW + slot;
    const bool nvalid = (n < N_NODES);
    const int nn = nvalid ? n : (N_NODES - 1);

    const float4 xr_c  = xr4[(size_t)nn * V4 + c4];
    const float4 att_c = ((const float4*)att)[c4];
    const float4 b_c   = ((const float4*)b)[c4];

    const int start = nn << LOG_MD;
    const int dg    = nvalid ? min(col[start + 63], ROWCAP) : 0;   // real edges

    // ---- self-loop contribution (xl[n] is coalesced) ----
    float4 xs4 = xl4[(size_t)nn * V4 + c4];
    float den;
    float4 acc;
    {
        float z0 = xs4.x + xr_c.x; z0 = (z0 >= 0.f) ? z0 : NEG_SLOPE * z0;
        float z1 = xs4.y + xr_c.y; z1 = (z1 >= 0.f) ? z1 : NEG_SLOPE * z1;
        float z2 = xs4.z + xr_c.z; z2 = (z2 >= 0.f) ? z2 : NEG_SLOPE * z2;
        float z3 = xs4.w + xr_c.w; z3 = (z3 >= 0.f) ? z3 : NEG_SLOPE * z3;
        float p = fmaf(z0, att_c.x, fmaf(z1, att_c.y, fmaf(z2, att_c.z, z3 * att_c.w)));
        #pragma unroll
        for (int off = HEADL / 2; off > 0; off >>= 1)
            p += __shfl_xor(p, off, 64);
        float ex = __expf(fminf(p, 80.f));
        den = ex;
        acc.x = ex * xs4.x; acc.y = ex * xs4.y; acc.z = ex * xs4.z; acc.w = ex * xs4.w;
    }

    // wave-wide max degree (all lanes active; loop is wave-uniform)
    int mdg = dg;
    #pragma unroll
    for (int off = 32; off > 0; off >>= 1) mdg = max(mdg, __shfl_xor(mdg, off, 64));

    float4 cur = xl4[(size_t)col[start] * V4 + c4];   // 0 if empty row (win zeroed)
    for (int k = 0; k < mdg; ++k) {
        float4 x4 = cur;
        if (k + 1 < mdg) {
            int kk = min(k + 1, dg - 1);
            if (kk < 0) kk = 0;
            int sn = col[start + kk];
            cur = xl4[(size_t)sn * V4 + c4];          // in flight during math below
        }
        float z0 = x4.x + xr_c.x; z0 = (z0 >= 0.f) ? z0 : NEG_SLOPE * z0;
        float z1 = x4.y + xr_c.y; z1 = (z1 >= 0.f) ? z1 : NEG_SLOPE * z1;
        float z2 = x4.z + xr_c.z; z2 = (z2 >= 0.f) ? z2 : NEG_SLOPE * z2;
        float z3 = x4.w + xr_c.w; z3 = (z3 >= 0.f) ? z3 : NEG_SLOPE * z3;
        float p = fmaf(z0, att_c.x, fmaf(z1, att_c.y, fmaf(z2, att_c.z, z3 * att_c.w)));
        #pragma unroll
        for (int off = HEADL / 2; off > 0; off >>= 1)
            p += __shfl_xor(p, off, 64);
        float ex = (k < dg) ? __expf(fminf(p, 80.f)) : 0.f;
        den += ex;
        acc.x = fmaf(ex, x4.x, acc.x);
        acc.y = fmaf(ex, x4.y, acc.y);
        acc.z = fmaf(ex, x4.z, acc.z);
        acc.w = fmaf(ex, x4.w, acc.w);
    }
    if (nvalid) {
        float inv = 1.f / den;
        float4 o;
        o.x = fmaf(acc.x, inv, b_c.x); o.x = (o.x > 0.f) ? o.x : (__expf(o.x) - 1.f);
        o.y = fmaf(acc.y, inv, b_c.y); o.y = (o.y > 0.f) ? o.y : (__expf(o.y) - 1.f);
        o.z = fmaf(acc.z, inv, b_c.z); o.z = (o.z > 0.f) ? o.z : (__expf(o.z) - 1.f);
        o.w = fmaf(acc.w, inv, b_c.w); o.w = (o.w > 0.f) ? o.w : (__expf(o.w) - 1.f);
        ((float4*)out)[(size_t)n * V4 + c4] = o;
    }
}

// ---------------- pool + head ----------------
// batch is sorted: accumulate runs locally, one atomic per run boundary.
__global__ void pool_k(const float* __restrict__ h2, const int* __restrict__ batch,
                       float* __restrict__ gsum, float* __restrict__ gcnt) {
    const int NCH = (N_NODES + 7) / 8;
    int t = blockIdx.x * blockDim.x + threadIdx.x;
    if (t >= NCH * 32) return;
    int c = t & 31;
    int n0 = (t >> 5) * 8;
    int nend = min(n0 + 8, N_NODES);
    int curb = batch[n0];
    float s = 0.f, cnt = 0.f;
    for (int n = n0; n < nend; ++n) {
        int bb = batch[n];
        if (bb != curb) {
            atomicAdd(gsum + (size_t)curb * 32 + c, s);
            if (c == 0) atomicAdd(gcnt + curb, cnt);
            s = 0.f; cnt = 0.f; curb = bb;
        }
        s += h2[(size_t)n * 32 + c];
        cnt += 1.f;
    }
    atomicAdd(gsum + (size_t)curb * 32 + c, s);
    if (c == 0) atomicAdd(gcnt + curb, cnt);
}

__global__ void head_k(const float* __restrict__ gsum, const float* __restrict__ gcnt,
                       const float* __restrict__ Wfc, const float* __restrict__ bfc,
                       float* __restrict__ out) {
    int gph = blockIdx.x * blockDim.x + threadIdx.x;
    if (gph >= NUM_GRAPHS) return;
    float inv = 1.f / fmaxf(gcnt[gph], 1.f);
    float logits[6];
    #pragma unroll
    for (int j = 0; j < 6; ++j) logits[j] = bfc[j];
    for (int k = 0; k < 32; ++k) {
        float p = gsum[(size_t)gph * 32 + k] * inv;
        #pragma unroll
        for (int j = 0; j < 6; ++j) logits[j] = fmaf(p, Wfc[k * 6 + j], logits[j]);
    }
    float m = logits[0];
    #pragma unroll
    for (int j = 1; j < 6; ++j) m = fmaxf(m, logits[j]);
    float ssum = 0.f;
    #pragma unroll
    for (int j = 0; j < 6; ++j) ssum += expf(logits[j] - m);
    float lse = m + logf(ssum);
    #pragma unroll
    for (int j = 0; j < 6; ++j) out[(size_t)gph * 6 + j] = logits[j] - lse;
}

extern "C" void kernel_launch(void* const* d_in, const int* in_sizes, int n_in,
                              void* d_out, int out_size, void* d_ws, size_t ws_size,
                              hipStream_t stream) {
    const float* x    = (const float*)d_in[0];
    const int*   ei   = (const int*)d_in[1];   // [2, N_EDGES]: row0 = src, row1 = dst
    const int*   batch= (const int*)d_in[2];
    const float* Wl1  = (const float*)d_in[3];
    const float* bl1  = (const float*)d_in[4];
    const float* Wr1  = (const float*)d_in[5];
    const float* att1 = (const float*)d_in[6];
    const float* b1   = (const float*)d_in[7];
    const float* Wl2  = (const float*)d_in[8];
    const float* bl2  = (const float*)d_in[9];
    const float* Wr2  = (const float*)d_in[10];
    const float* att2 = (const float*)d_in[11];
    const float* b2   = (const float*)d_in[12];
    const float* Wfc  = (const float*)d_in[13];
    const float* bfc  = (const float*)d_in[14];
    float* out = (float*)d_out;

    // ---- workspace layout ----
    char* wsp = (char*)d_ws;
    float* xl1  = (float*)wsp; wsp += (size_t)N_NODES * 64 * 4;
    float* xr1  = (float*)wsp; wsp += (size_t)N_NODES * 64 * 4;
    float* h1   = (float*)wsp; wsp += (size_t)N_NODES * 64 * 4;
    float* xl2  = (float*)wsp; wsp += (size_t)N_NODES * 32 * 4;
    float* xr2  = (float*)wsp; wsp += (size_t)N_NODES * 32 * 4;
    float* h2   = (float*)wsp; wsp += (size_t)N_NODES * 32 * 4;
    float* gsum = (float*)wsp; wsp += (size_t)NUM_GRAPHS * 32 * 4;   // gsum+gcnt adjacent
    float* gcnt = (float*)wsp; wsp += (size_t)NUM_GRAPHS * 4;
    int* col    = (int*)wsp; wsp += ((size_t)N_NODES << LOG_MD) * 4; // 12.8 MB padded CSR
    int* bucket_cnt = (int*)wsp; wsp += NBKT * 4;
    int* bucket_off = (int*)wsp; wsp += NBKT * 4;
    int* bucket_cur = (int*)wsp; wsp += NBKT * 4;
    int2* binned = (int2*)h1;   // alias: dead before conv1 writes h1

    const int TB = 256;

    // ---- binned CSR build ----
    hipMemsetAsync(bucket_cnt, 0, NBKT * sizeof(int), stream);
    hist_k<<<NPART, 256, 0, stream>>>(ei + N_EDGES, bucket_cnt, gsum);
    bscan_k<<<1, 256, 0, stream>>>(bucket_cnt, bucket_off, bucket_cur);
    part_k<<<NPART, 256, 0, stream>>>(ei, bucket_cur, binned);
    build_k<<<NBKT, 256, 0, stream>>>(bucket_off, binned, col);

    // ---- layer 1 ----
    node_linear2_k<128, 64, 16><<<(N_NODES + 15) / 16, 256, 0, stream>>>(
        x, Wl1, bl1, Wr1, xl1, xr1);
    {   // 16 lanes/node -> 4 nodes/wave
        int waves = (N_NODES + 3) / 4;
        gat_conv_k<64, 16, 8><<<(waves + 3) / 4, 256, 0, stream>>>(
            col, (const float4*)xl1, (const float4*)xr1, att1, b1, h1);
    }

    // ---- layer 2 ----
    node_linear2_k<64, 32, 32><<<(N_NODES + 31) / 32, 256, 0, stream>>>(
        h1, Wl2, bl2, Wr2, xl2, xr2);
    {   // 8 lanes/node -> 8 nodes/wave
        int waves = (N_NODES + 7) / 8;
        gat_conv_k<32, 8, 4><<<(waves + 3) / 4, 256, 0, stream>>>(
            col, (const float4*)xl2, (const float4*)xr2, att2, b2, h2);
    }

    // ---- pool + head (gsum/gcnt zeroed inside hist_k) ----
    pool_k<<<(((N_NODES + 7) / 8) * 32 + TB - 1) / TB, TB, 0, stream>>>(h2, batch, gsum, gcnt);
    head_k<<<(NUM_GRAPHS + TB - 1) / TB, TB, 0, stream>>>(gsum, gcnt, Wfc, bfc, out);
}

// Round 8
// 270.803 us; speedup vs baseline: 1.0587x; 1.0131x over previous
//
#include <hip/hip_runtime.h>
#include <math.h>

#define N_NODES 50000
#define N_EDGES 800000
#define NUM_GRAPHS 512
#define NEG_SLOPE 0.2f
#define LOG_MD 6
#define ROWCAP 63          // slots 0..62 = real edges; slot 63 = real-edge count
#define NBKT 196           // ceil(50000/256) buckets of 256 dst nodes
#define NPART 200
#define EPB_PART 4000      // NPART * EPB_PART == N_EDGES

// ---------------- stage 1: per-bucket histogram (+ zero gsum/gcnt) ----------------
__global__ void hist_k(const int* __restrict__ ei_dst, int* __restrict__ bucket_cnt,
                       float* __restrict__ gz) {
    __shared__ int h[NBKT];
    const int tid = threadIdx.x;
    for (int i = tid; i < NBKT; i += 256) h[i] = 0;
    int gt = blockIdx.x * 256 + tid;                  // 51200 threads cover 16896
    if (gt < NUM_GRAPHS * 33) gz[gt] = 0.f;           // gsum (512*32) + gcnt (512)
    __syncthreads();
    const int base = blockIdx.x * EPB_PART;
    for (int i = tid; i < EPB_PART; i += 256)
        atomicAdd(&h[ei_dst[base + i] >> 8], 1);
    __syncthreads();
    for (int i = tid; i < NBKT; i += 256)
        if (h[i]) atomicAdd(&bucket_cnt[i], h[i]);
}

// ---------------- stage 2: scan bucket counts ----------------
__global__ void bscan_k(const int* __restrict__ bucket_cnt,
                        int* __restrict__ bucket_off, int* __restrict__ bucket_cur) {
    __shared__ int s[256];
    int tid = threadIdx.x;
    s[tid] = (tid < NBKT) ? bucket_cnt[tid] : 0;
    __syncthreads();
    for (int off = 1; off < 256; off <<= 1) {
        int v = (tid >= off) ? s[tid - off] : 0;
        __syncthreads();
        s[tid] += v;
        __syncthreads();
    }
    if (tid < NBKT) {
        int excl = (tid == 0) ? 0 : s[tid - 1];
        bucket_off[tid] = excl;
        bucket_cur[tid] = excl;
    }
}

// ---------------- stage 3: partition edges into bucket-grouped runs ----------------
__global__ void __launch_bounds__(256) part_k(const int* __restrict__ ei,
                                              int* __restrict__ bucket_cur,
                                              int2* __restrict__ binned) {
    __shared__ int2 ebuf[EPB_PART];   // 32 KB
    __shared__ int2 sbuf[EPB_PART];   // 32 KB
    __shared__ int hist[NBKT], loff[NBKT], rk[NBKT], gbase[NBKT];
    __shared__ int s2[256];
    const int tid = threadIdx.x;
    for (int i = tid; i < NBKT; i += 256) { hist[i] = 0; rk[i] = 0; }
    __syncthreads();
    const int base = blockIdx.x * EPB_PART;
    for (int i = tid; i < EPB_PART; i += 256) {
        int s = ei[base + i];
        int d = ei[N_EDGES + base + i];
        ebuf[i] = make_int2(s, d);
        atomicAdd(&hist[d >> 8], 1);
    }
    __syncthreads();
    // exclusive scan of hist -> loff
    s2[tid] = (tid < NBKT) ? hist[tid] : 0;
    __syncthreads();
    for (int off = 1; off < 256; off <<= 1) {
        int v = (tid >= off) ? s2[tid - off] : 0;
        __syncthreads();
        s2[tid] += v;
        __syncthreads();
    }
    if (tid < NBKT) {
        loff[tid] = (tid == 0) ? 0 : s2[tid - 1];
        gbase[tid] = hist[tid] ? atomicAdd(&bucket_cur[tid], hist[tid]) : 0;
    }
    __syncthreads();
    // reorder into bucket-grouped LDS staging
    for (int i = tid; i < EPB_PART; i += 256) {
        int2 e = ebuf[i];
        int b = e.y >> 8;
        int r = atomicAdd(&rk[b], 1);
        sbuf[loff[b] + r] = e;
    }
    __syncthreads();
    // linear write-out: consecutive threads -> mostly-contiguous global runs
    for (int i = tid; i < EPB_PART; i += 256) {
        int2 e = sbuf[i];
        int b = e.y >> 8;
        binned[gbase[b] + (i - loff[b])] = e;
    }
}

// ---------------- stage 4: build padded CSR rows in LDS, write coalesced ----------------
__global__ void __launch_bounds__(256) build_k(const int* __restrict__ bucket_off,
                                               const int2* __restrict__ binned,
                                               int* __restrict__ col) {
    __shared__ int win[256 * ROWCAP];   // 63 KB
    __shared__ int cnt[256];
    const int tid = threadIdx.x;
    for (int i = tid; i < 256 * ROWCAP; i += 256) win[i] = 0;
    if (tid < 256) cnt[tid] = 0;
    __syncthreads();
    const int b = blockIdx.x;
    const int beg = bucket_off[b];
    const int end = (b == NBKT - 1) ? N_EDGES : bucket_off[b + 1];
    for (int i = beg + tid; i < end; i += 256) {
        int2 e = binned[i];
        int row = e.y & 255;
        int c = atomicAdd(&cnt[row], 1);
        if (c < ROWCAP) win[row * ROWCAP + c] = e.x;
    }
    __syncthreads();
    const int n0 = b << 8;
    const int nrows = min(256, N_NODES - n0);
    int* dst = col + ((size_t)n0 << LOG_MD);
    for (int i = tid; i < nrows * 64; i += 256) {
        int row = i >> 6, s = i & 63;
        dst[i] = (s == 63) ? min(cnt[row], ROWCAP) : win[row * ROWCAP + s];
    }
}

// ---------------- tiled node linear, W staged in LDS chunks ----------------
// Inner loop reads ONLY LDS: x-tile (broadcast b128) + W chunk (conflict-free
// scalar). No global loads in the hot loop -> low VGPR -> 4+ blocks/CU.
template<int FIN, int FOUT, int NPB, int KC>
__global__ void __launch_bounds__(256) node_linear2_k(
        const float* __restrict__ x,
        const float* __restrict__ Wl, const float* __restrict__ bl,
        const float* __restrict__ Wr,
        float* __restrict__ xl, float* __restrict__ xr) {
    const int GROUPS = 256 / FOUT;   // thread groups, FOUT threads each
    const int NPG = NPB / GROUPS;    // nodes per thread
    __shared__ float xs[NPB * FIN];
    __shared__ float wls[KC * FOUT];
    __shared__ float wrs[KC * FOUT];
    const int tid = threadIdx.x;
    const int n0_blk = blockIdx.x * NPB;
    const int nodes_here = min(NPB, N_NODES - n0_blk);

    const float4* xv = (const float4*)(x + (size_t)n0_blk * FIN);
    const int total4 = nodes_here * FIN / 4;
    for (int i = tid; i < total4; i += 256) ((float4*)xs)[i] = xv[i];

    const int j = tid % FOUT;
    const int g = tid / FOUT;
    float al[NPG], ar[NPG];
    const float blj = bl[j];
    #pragma unroll
    for (int i = 0; i < NPG; ++i) { al[i] = blj; ar[i] = 0.f; }

    const float* xbase = xs + (size_t)g * NPG * FIN;
    for (int kc = 0; kc < FIN; kc += KC) {
        __syncthreads();   // xs ready (iter 0) / previous chunk consumed
        const int CH4 = KC * FOUT / 4;
        const float4* wl4p = (const float4*)(Wl + (size_t)kc * FOUT);
        const float4* wr4p = (const float4*)(Wr + (size_t)kc * FOUT);
        for (int i = tid; i < CH4; i += 256) {
            ((float4*)wls)[i] = wl4p[i];
            ((float4*)wrs)[i] = wr4p[i];
        }
        __syncthreads();
        for (int k = 0; k < KC; k += 4) {
            float wl0 = wls[(k + 0) * FOUT + j], wl1 = wls[(k + 1) * FOUT + j];
            float wl2 = wls[(k + 2) * FOUT + j], wl3 = wls[(k + 3) * FOUT + j];
            float wr0 = wrs[(k + 0) * FOUT + j], wr1 = wrs[(k + 1) * FOUT + j];
            float wr2 = wrs[(k + 2) * FOUT + j], wr3 = wrs[(k + 3) * FOUT + j];
            #pragma unroll
            for (int i = 0; i < NPG; ++i) {
                float4 v = *(const float4*)(xbase + i * FIN + kc + k);  // LDS broadcast
                al[i] = fmaf(v.x, wl0, fmaf(v.y, wl1, fmaf(v.z, wl2, fmaf(v.w, wl3, al[i]))));
                ar[i] = fmaf(v.x, wr0, fmaf(v.y, wr1, fmaf(v.z, wr2, fmaf(v.w, wr3, ar[i]))));
            }
        }
    }
    const int nbase = n0_blk + g * NPG;
    #pragma unroll
    for (int i = 0; i < NPG; ++i) {
        int n = nbase + i;
        if (n < N_NODES) {
            xl[(size_t)n * FOUT + j] = al[i];
            xr[(size_t)n * FOUT + j] = ar[i];
        }
    }
}

// ---------------- fused GATv2 conv, float4 channels, padded CSR ----------------
// Self loop handled implicitly (xl[n] is a coalesced load); rows hold real
// edges only, count at slot 63. Softmax shift-invariance: no max subtraction.
template<int C2, int LPN, int HEADL>   // channels, lanes/node = C2/4, lanes/head = LPN/2
__global__ void gat_conv_k(const int* __restrict__ col,
                           const float4* __restrict__ xl4, const float4* __restrict__ xr4,
                           const float* __restrict__ att, const float* __restrict__ b,
                           float* __restrict__ out) {
    const int NPW = 64 / LPN;
    const int V4  = C2 / 4;      // float4s per node row (== LPN)
    int wave = (blockIdx.x * blockDim.x + threadIdx.x) >> 6;
    int lane = threadIdx.x & 63;
    int slot = lane / LPN;
    int c4   = lane % LPN;
    int n = wave * NPW + slot;
    const bool nvalid = (n < N_NODES);
    const int nn = nvalid ? n : (N_NODES - 1);

    const float4 xr_c  = xr4[(size_t)nn * V4 + c4];
    const float4 att_c = ((const float4*)att)[c4];
    const float4 b_c   = ((const float4*)b)[c4];

    const int start = nn << LOG_MD;
    const int dg    = nvalid ? min(col[start + 63], ROWCAP) : 0;   // real edges

    // ---- self-loop contribution (xl[n] is coalesced) ----
    float4 xs4 = xl4[(size_t)nn * V4 + c4];
    float den;
    float4 acc;
    {
        float z0 = xs4.x + xr_c.x; z0 = (z0 >= 0.f) ? z0 : NEG_SLOPE * z0;
        float z1 = xs4.y + xr_c.y; z1 = (z1 >= 0.f) ? z1 : NEG_SLOPE * z1;
        float z2 = xs4.z + xr_c.z; z2 = (z2 >= 0.f) ? z2 : NEG_SLOPE * z2;
        float z3 = xs4.w + xr_c.w; z3 = (z3 >= 0.f) ? z3 : NEG_SLOPE * z3;
        float p = fmaf(z0, att_c.x, fmaf(z1, att_c.y, fmaf(z2, att_c.z, z3 * att_c.w)));
        #pragma unroll
        for (int off = HEADL / 2; off > 0; off >>= 1)
            p += __shfl_xor(p, off, 64);
        float ex = __expf(fminf(p, 80.f));
        den = ex;
        acc.x = ex * xs4.x; acc.y = ex * xs4.y; acc.z = ex * xs4.z; acc.w = ex * xs4.w;
    }

    // wave-wide max degree (all lanes active; loop is wave-uniform)
    int mdg = dg;
    #pragma unroll
    for (int off = 32; off > 0; off >>= 1) mdg = max(mdg, __shfl_xor(mdg, off, 64));

    float4 cur = xl4[(size_t)col[start] * V4 + c4];   // 0 if empty row (win zeroed)
    for (int k = 0; k < mdg; ++k) {
        float4 x4 = cur;
        if (k + 1 < mdg) {
            int kk = min(k + 1, dg - 1);
            if (kk < 0) kk = 0;
            int sn = col[start + kk];
            cur = xl4[(size_t)sn * V4 + c4];          // in flight during math below
        }
        float z0 = x4.x + xr_c.x; z0 = (z0 >= 0.f) ? z0 : NEG_SLOPE * z0;
        float z1 = x4.y + xr_c.y; z1 = (z1 >= 0.f) ? z1 : NEG_SLOPE * z1;
        float z2 = x4.z + xr_c.z; z2 = (z2 >= 0.f) ? z2 : NEG_SLOPE * z2;
        float z3 = x4.w + xr_c.w; z3 = (z3 >= 0.f) ? z3 : NEG_SLOPE * z3;
        float p = fmaf(z0, att_c.x, fmaf(z1, att_c.y, fmaf(z2, att_c.z, z3 * att_c.w)));
        #pragma unroll
        for (int off = HEADL / 2; off > 0; off >>= 1)
            p += __shfl_xor(p, off, 64);
        float ex = (k < dg) ? __expf(fminf(p, 80.f)) : 0.f;
        den += ex;
        acc.x = fmaf(ex, x4.x, acc.x);
        acc.y = fmaf(ex, x4.y, acc.y);
        acc.z = fmaf(ex, x4.z, acc.z);
        acc.w = fmaf(ex, x4.w, acc.w);
    }
    if (nvalid) {
        float inv = 1.f / den;
        float4 o;
        o.x = fmaf(acc.x, inv, b_c.x); o.x = (o.x > 0.f) ? o.x : (__expf(o.x) - 1.f);
        o.y = fmaf(acc.y, inv, b_c.y); o.y = (o.y > 0.f) ? o.y : (__expf(o.y) - 1.f);
        o.z = fmaf(acc.z, inv, b_c.z); o.z = (o.z > 0.f) ? o.z : (__expf(o.z) - 1.f);
        o.w = fmaf(acc.w, inv, b_c.w); o.w = (o.w > 0.f) ? o.w : (__expf(o.w) - 1.f);
        ((float4*)out)[(size_t)n * V4 + c4] = o;
    }
}

// ---------------- pool + head ----------------
// batch is sorted: accumulate runs locally, one atomic per run boundary.
__global__ void pool_k(const float* __restrict__ h2, const int* __restrict__ batch,
                       float* __restrict__ gsum, float* __restrict__ gcnt) {
    const int NCH = (N_NODES + 7) / 8;
    int t = blockIdx.x * blockDim.x + threadIdx.x;
    if (t >= NCH * 32) return;
    int c = t & 31;
    int n0 = (t >> 5) * 8;
    int nend = min(n0 + 8, N_NODES);
    int curb = batch[n0];
    float s = 0.f, cnt = 0.f;
    for (int n = n0; n < nend; ++n) {
        int bb = batch[n];
        if (bb != curb) {
            atomicAdd(gsum + (size_t)curb * 32 + c, s);
            if (c == 0) atomicAdd(gcnt + curb, cnt);
            s = 0.f; cnt = 0.f; curb = bb;
        }
        s += h2[(size_t)n * 32 + c];
        cnt += 1.f;
    }
    atomicAdd(gsum + (size_t)curb * 32 + c, s);
    if (c == 0) atomicAdd(gcnt + curb, cnt);
}

__global__ void head_k(const float* __restrict__ gsum, const float* __restrict__ gcnt,
                       const float* __restrict__ Wfc, const float* __restrict__ bfc,
                       float* __restrict__ out) {
    int gph = blockIdx.x * blockDim.x + threadIdx.x;
    if (gph >= NUM_GRAPHS) return;
    float inv = 1.f / fmaxf(gcnt[gph], 1.f);
    float logits[6];
    #pragma unroll
    for (int j = 0; j < 6; ++j) logits[j] = bfc[j];
    for (int k = 0; k < 32; ++k) {
        float p = gsum[(size_t)gph * 32 + k] * inv;
        #pragma unroll
        for (int j = 0; j < 6; ++j) logits[j] = fmaf(p, Wfc[k * 6 + j], logits[j]);
    }
    float m = logits[0];
    #pragma unroll
    for (int j = 1; j < 6; ++j) m = fmaxf(m, logits[j]);
    float ssum = 0.f;
    #pragma unroll
    for (int j = 0; j < 6; ++j) ssum += expf(logits[j] - m);
    float lse = m + logf(ssum);
    #pragma unroll
    for (int j = 0; j < 6; ++j) out[(size_t)gph * 6 + j] = logits[j] - lse;
}

extern "C" void kernel_launch(void* const* d_in, const int* in_sizes, int n_in,
                              void* d_out, int out_size, void* d_ws, size_t ws_size,
                              hipStream_t stream) {
    const float* x    = (const float*)d_in[0];
    const int*   ei   = (const int*)d_in[1];   // [2, N_EDGES]: row0 = src, row1 = dst
    const int*   batch= (const int*)d_in[2];
    const float* Wl1  = (const float*)d_in[3];
    const float* bl1  = (const float*)d_in[4];
    const float* Wr1  = (const float*)d_in[5];
    const float* att1 = (const float*)d_in[6];
    const float* b1   = (const float*)d_in[7];
    const float* Wl2  = (const float*)d_in[8];
    const float* bl2  = (const float*)d_in[9];
    const float* Wr2  = (const float*)d_in[10];
    const float* att2 = (const float*)d_in[11];
    const float* b2   = (const float*)d_in[12];
    const float* Wfc  = (const float*)d_in[13];
    const float* bfc  = (const float*)d_in[14];
    float* out = (float*)d_out;

    // ---- workspace layout ----
    char* wsp = (char*)d_ws;
    float* xl1  = (float*)wsp; wsp += (size_t)N_NODES * 64 * 4;
    float* xr1  = (float*)wsp; wsp += (size_t)N_NODES * 64 * 4;
    float* h1   = (float*)wsp; wsp += (size_t)N_NODES * 64 * 4;
    float* xl2  = (float*)wsp; wsp += (size_t)N_NODES * 32 * 4;
    float* xr2  = (float*)wsp; wsp += (size_t)N_NODES * 32 * 4;
    float* h2   = (float*)wsp; wsp += (size_t)N_NODES * 32 * 4;
    float* gsum = (float*)wsp; wsp += (size_t)NUM_GRAPHS * 32 * 4;   // gsum+gcnt adjacent
    float* gcnt = (float*)wsp; wsp += (size_t)NUM_GRAPHS * 4;
    int* col    = (int*)wsp; wsp += ((size_t)N_NODES << LOG_MD) * 4; // 12.8 MB padded CSR
    int* bucket_cnt = (int*)wsp; wsp += NBKT * 4;
    int* bucket_off = (int*)wsp; wsp += NBKT * 4;
    int* bucket_cur = (int*)wsp; wsp += NBKT * 4;
    int2* binned = (int2*)h1;   // alias: dead before conv1 writes h1

    const int TB = 256;

    // ---- binned CSR build ----
    hipMemsetAsync(bucket_cnt, 0, NBKT * sizeof(int), stream);
    hist_k<<<NPART, 256, 0, stream>>>(ei + N_EDGES, bucket_cnt, gsum);
    bscan_k<<<1, 256, 0, stream>>>(bucket_cnt, bucket_off, bucket_cur);
    part_k<<<NPART, 256, 0, stream>>>(ei, bucket_cur, binned);
    build_k<<<NBKT, 256, 0, stream>>>(bucket_off, binned, col);

    // ---- layer 1 ----
    node_linear2_k<128, 64, 32, 32><<<(N_NODES + 31) / 32, 256, 0, stream>>>(
        x, Wl1, bl1, Wr1, xl1, xr1);
    {   // 16 lanes/node -> 4 nodes/wave
        int waves = (N_NODES + 3) / 4;
        gat_conv_k<64, 16, 8><<<(waves + 3) / 4, 256, 0, stream>>>(
            col, (const float4*)xl1, (const float4*)xr1, att1, b1, h1);
    }

    // ---- layer 2 ----
    node_linear2_k<64, 32, 64, 32><<<(N_NODES + 63) / 64, 256, 0, stream>>>(
        h1, Wl2, bl2, Wr2, xl2, xr2);
    {   // 8 lanes/node -> 8 nodes/wave
        int waves = (N_NODES + 7) / 8;
        gat_conv_k<32, 8, 4><<<(waves + 3) / 4, 256, 0, stream>>>(
            col, (const float4*)xl2, (const float4*)xr2, att2, b2, h2);
    }

    // ---- pool + head (gsum/gcnt zeroed inside hist_k) ----
    pool_k<<<(((N_NODES + 7) / 8) * 32 + TB - 1) / TB, TB, 0, stream>>>(h2, batch, gsum, gcnt);
    head_k<<<(NUM_GRAPHS + TB - 1) / TB, TB, 0, stream>>>(gsum, gcnt, Wfc, bfc, out);
}

// Round 9
// 268.792 us; speedup vs baseline: 1.0666x; 1.0075x over previous
//
#include <hip/hip_runtime.h>
#include <math.h>

#define N_NODES 50000
#define N_EDGES 800000
#define NUM_GRAPHS 512
#define NEG_SLOPE 0.2f
#define LOG_MD 6
#define ROWCAP 63          // slots 0..62 = real edges; slot 63 = real-edge count
#define NBKT 196           // ceil(50000/256) buckets of 256 dst nodes
#define NPART 200
#define EPB_PART 4000      // NPART * EPB_PART == N_EDGES

// ---------------- stage 1: per-bucket histogram (+ zero gsum/gcnt) ----------------
__global__ void hist_k(const int* __restrict__ ei_dst, int* __restrict__ bucket_cnt,
                       float* __restrict__ gz) {
    __shared__ int h[NBKT];
    const int tid = threadIdx.x;
    for (int i = tid; i < NBKT; i += 256) h[i] = 0;
    int gt = blockIdx.x * 256 + tid;                  // 51200 threads cover 16896
    if (gt < NUM_GRAPHS * 33) gz[gt] = 0.f;           // gsum (512*32) + gcnt (512)
    __syncthreads();
    const int base = blockIdx.x * EPB_PART;
    for (int i = tid; i < EPB_PART; i += 256)
        atomicAdd(&h[ei_dst[base + i] >> 8], 1);
    __syncthreads();
    for (int i = tid; i < NBKT; i += 256)
        if (h[i]) atomicAdd(&bucket_cnt[i], h[i]);
}

// ---------------- stage 2: scan bucket counts ----------------
__global__ void bscan_k(const int* __restrict__ bucket_cnt,
                        int* __restrict__ bucket_off, int* __restrict__ bucket_cur) {
    __shared__ int s[256];
    int tid = threadIdx.x;
    s[tid] = (tid < NBKT) ? bucket_cnt[tid] : 0;
    __syncthreads();
    for (int off = 1; off < 256; off <<= 1) {
        int v = (tid >= off) ? s[tid - off] : 0;
        __syncthreads();
        s[tid] += v;
        __syncthreads();
    }
    if (tid < NBKT) {
        int excl = (tid == 0) ? 0 : s[tid - 1];
        bucket_off[tid] = excl;
        bucket_cur[tid] = excl;
    }
}

// ---------------- stage 3: partition edges into bucket-grouped runs ----------------
__global__ void __launch_bounds__(256) part_k(const int* __restrict__ ei,
                                              int* __restrict__ bucket_cur,
                                              int2* __restrict__ binned) {
    __shared__ int2 ebuf[EPB_PART];   // 32 KB
    __shared__ int2 sbuf[EPB_PART];   // 32 KB
    __shared__ int hist[NBKT], loff[NBKT], rk[NBKT], gbase[NBKT];
    __shared__ int s2[256];
    const int tid = threadIdx.x;
    for (int i = tid; i < NBKT; i += 256) { hist[i] = 0; rk[i] = 0; }
    __syncthreads();
    const int base = blockIdx.x * EPB_PART;
    for (int i = tid; i < EPB_PART; i += 256) {
        int s = ei[base + i];
        int d = ei[N_EDGES + base + i];
        ebuf[i] = make_int2(s, d);
        atomicAdd(&hist[d >> 8], 1);
    }
    __syncthreads();
    // exclusive scan of hist -> loff
    s2[tid] = (tid < NBKT) ? hist[tid] : 0;
    __syncthreads();
    for (int off = 1; off < 256; off <<= 1) {
        int v = (tid >= off) ? s2[tid - off] : 0;
        __syncthreads();
        s2[tid] += v;
        __syncthreads();
    }
    if (tid < NBKT) {
        loff[tid] = (tid == 0) ? 0 : s2[tid - 1];
        gbase[tid] = hist[tid] ? atomicAdd(&bucket_cur[tid], hist[tid]) : 0;
    }
    __syncthreads();
    // reorder into bucket-grouped LDS staging
    for (int i = tid; i < EPB_PART; i += 256) {
        int2 e = ebuf[i];
        int b = e.y >> 8;
        int r = atomicAdd(&rk[b], 1);
        sbuf[loff[b] + r] = e;
    }
    __syncthreads();
    // linear write-out: consecutive threads -> mostly-contiguous global runs
    for (int i = tid; i < EPB_PART; i += 256) {
        int2 e = sbuf[i];
        int b = e.y >> 8;
        binned[gbase[b] + (i - loff[b])] = e;
    }
}

// ---------------- stage 4: build padded CSR rows in LDS, write coalesced ----------------
__global__ void __launch_bounds__(256) build_k(const int* __restrict__ bucket_off,
                                               const int2* __restrict__ binned,
                                               int* __restrict__ col) {
    __shared__ int win[256 * ROWCAP];   // 63 KB
    __shared__ int cnt[256];
    const int tid = threadIdx.x;
    for (int i = tid; i < 256 * ROWCAP; i += 256) win[i] = 0;
    if (tid < 256) cnt[tid] = 0;
    __syncthreads();
    const int b = blockIdx.x;
    const int beg = bucket_off[b];
    const int end = (b == NBKT - 1) ? N_EDGES : bucket_off[b + 1];
    for (int i = beg + tid; i < end; i += 256) {
        int2 e = binned[i];
        int row = e.y & 255;
        int c = atomicAdd(&cnt[row], 1);
        if (c < ROWCAP) win[row * ROWCAP + c] = e.x;
    }
    __syncthreads();
    const int n0 = b << 8;
    const int nrows = min(256, N_NODES - n0);
    int* dst = col + ((size_t)n0 << LOG_MD);
    for (int i = tid; i < nrows * 64; i += 256) {
        int row = i >> 6, s = i & 63;
        dst[i] = (s == 63) ? min(cnt[row], ROWCAP) : win[row * ROWCAP + s];
    }
}

// ---------------- node linear, x via wave-uniform scalar loads ----------------
// Layer-1 variant: FOUT=64, lane = output column, dual L/R accumulators.
// x addresses depend only on (block, wave, i, k) -> wave-uniform -> SMEM pipe.
// Inner loop LDS traffic: 8 ds_read_b32 (W) per 4-k step vs 128 FMA cycles.
template<int FIN, int FOUT, int NPG, int KC>
__global__ void __launch_bounds__(256) node_linear_dual_k(
        const float* __restrict__ x,
        const float* __restrict__ Wl, const float* __restrict__ bl,
        const float* __restrict__ Wr,
        float* __restrict__ xl, float* __restrict__ xr) {
    const int NPB = 4 * NPG;   // 4 waves/block
    __shared__ float wls[KC * FOUT];
    __shared__ float wrs[KC * FOUT];
    const int tid = threadIdx.x;
    const int lane = tid & 63;
    const int gu = __builtin_amdgcn_readfirstlane(tid >> 6);   // wave id, uniform
    const int n0 = blockIdx.x * NPB + gu * NPG;
    const int j = lane;

    float al[NPG], ar[NPG];
    const float blj = bl[j];
    #pragma unroll
    for (int i = 0; i < NPG; ++i) { al[i] = blj; ar[i] = 0.f; }

    for (int kc = 0; kc < FIN; kc += KC) {
        __syncthreads();
        const int CH4 = KC * FOUT / 4;
        const float4* wl4p = (const float4*)(Wl + (size_t)kc * FOUT);
        const float4* wr4p = (const float4*)(Wr + (size_t)kc * FOUT);
        for (int i = tid; i < CH4; i += 256) {
            ((float4*)wls)[i] = wl4p[i];
            ((float4*)wrs)[i] = wr4p[i];
        }
        __syncthreads();
        #pragma unroll
        for (int k = 0; k < KC; k += 4) {
            float wl0 = wls[(k + 0) * FOUT + j], wl1 = wls[(k + 1) * FOUT + j];
            float wl2 = wls[(k + 2) * FOUT + j], wl3 = wls[(k + 3) * FOUT + j];
            float wr0 = wrs[(k + 0) * FOUT + j], wr1 = wrs[(k + 1) * FOUT + j];
            float wr2 = wrs[(k + 2) * FOUT + j], wr3 = wrs[(k + 3) * FOUT + j];
            #pragma unroll
            for (int i = 0; i < NPG; ++i) {
                int row = min(n0 + i, N_NODES - 1);   // uniform; clamp OOB tail
                const float4 v = *(const float4*)(x + (size_t)row * FIN + kc + k);
                al[i] = fmaf(v.x, wl0, fmaf(v.y, wl1, fmaf(v.z, wl2, fmaf(v.w, wl3, al[i]))));
                ar[i] = fmaf(v.x, wr0, fmaf(v.y, wr1, fmaf(v.z, wr2, fmaf(v.w, wr3, ar[i]))));
            }
        }
    }
    #pragma unroll
    for (int i = 0; i < NPG; ++i) {
        int n = n0 + i;
        if (n < N_NODES) {
            xl[(size_t)n * FOUT + j] = al[i];
            xr[(size_t)n * FOUT + j] = ar[i];
        }
    }
}

// Layer-2 variant: FOUT=32. Lanes 0..31 compute Wl columns (+bias), lanes
// 32..63 compute Wr columns, SAME node group -> x reads stay wave-uniform.
template<int FIN, int FOUT, int NPG, int KC>
__global__ void __launch_bounds__(256) node_linear_split_k(
        const float* __restrict__ x,
        const float* __restrict__ Wl, const float* __restrict__ bl,
        const float* __restrict__ Wr,
        float* __restrict__ xl, float* __restrict__ xr) {
    const int NPB = 4 * NPG;
    __shared__ float ws2[2][KC * FOUT];
    const int tid = threadIdx.x;
    const int lane = tid & 63;
    const int gu = __builtin_amdgcn_readfirstlane(tid >> 6);
    const int n0 = blockIdx.x * NPB + gu * NPG;
    const int j = lane & (FOUT - 1);
    const int sel = lane >> 5;   // 0 = L, 1 = R (FOUT == 32)

    float a[NPG];
    const float binit = sel ? 0.f : bl[j];
    #pragma unroll
    for (int i = 0; i < NPG; ++i) a[i] = binit;

    for (int kc = 0; kc < FIN; kc += KC) {
        __syncthreads();
        const int CH4 = KC * FOUT / 4;
        const float4* wl4p = (const float4*)(Wl + (size_t)kc * FOUT);
        const float4* wr4p = (const float4*)(Wr + (size_t)kc * FOUT);
        for (int i = tid; i < CH4; i += 256) {
            ((float4*)ws2[0])[i] = wl4p[i];
            ((float4*)ws2[1])[i] = wr4p[i];
        }
        __syncthreads();
        const float* ws = ws2[sel];
        #pragma unroll
        for (int k = 0; k < KC; k += 4) {
            float w0 = ws[(k + 0) * FOUT + j], w1 = ws[(k + 1) * FOUT + j];
            float w2 = ws[(k + 2) * FOUT + j], w3 = ws[(k + 3) * FOUT + j];
            #pragma unroll
            for (int i = 0; i < NPG; ++i) {
                int row = min(n0 + i, N_NODES - 1);
                const float4 v = *(const float4*)(x + (size_t)row * FIN + kc + k);
                a[i] = fmaf(v.x, w0, fmaf(v.y, w1, fmaf(v.z, w2, fmaf(v.w, w3, a[i]))));
            }
        }
    }
    float* dst = sel ? xr : xl;
    #pragma unroll
    for (int i = 0; i < NPG; ++i) {
        int n = n0 + i;
        if (n < N_NODES) dst[(size_t)n * FOUT + j] = a[i];
    }
}

// ---------------- fused GATv2 conv, float4 channels, padded CSR ----------------
// Self loop handled implicitly (xl[n] is a coalesced load); rows hold real
// edges only, count at slot 63. Softmax shift-invariance: no max subtraction.
template<int C2, int LPN, int HEADL>   // channels, lanes/node = C2/4, lanes/head = LPN/2
__global__ void gat_conv_k(const int* __restrict__ col,
                           const float4* __restrict__ xl4, const float4* __restrict__ xr4,
                           const float* __restrict__ att, const float* __restrict__ b,
                           float* __restrict__ out) {
    const int NPW = 64 / LPN;
    const int V4  = C2 / 4;      // float4s per node row (== LPN)
    int wave = (blockIdx.x * blockDim.x + threadIdx.x) >> 6;
    int lane = threadIdx.x & 63;
    int slot = lane / LPN;
    int c4   = lane % LPN;
    int n = wave * NPW + slot;
    const bool nvalid = (n < N_NODES);
    const int nn = nvalid ? n : (N_NODES - 1);

    const float4 xr_c  = xr4[(size_t)nn * V4 + c4];
    const float4 att_c = ((const float4*)att)[c4];
    const float4 b_c   = ((const float4*)b)[c4];

    const int start = nn << LOG_MD;
    const int dg    = nvalid ? min(col[start + 63], ROWCAP) : 0;   // real edges

    // ---- self-loop contribution (xl[n] is coalesced) ----
    float4 xs4 = xl4[(size_t)nn * V4 + c4];
    float den;
    float4 acc;
    {
        float z0 = xs4.x + xr_c.x; z0 = (z0 >= 0.f) ? z0 : NEG_SLOPE * z0;
        float z1 = xs4.y + xr_c.y; z1 = (z1 >= 0.f) ? z1 : NEG_SLOPE * z1;
        float z2 = xs4.z + xr_c.z; z2 = (z2 >= 0.f) ? z2 : NEG_SLOPE * z2;
        float z3 = xs4.w + xr_c.w; z3 = (z3 >= 0.f) ? z3 : NEG_SLOPE * z3;
        float p = fmaf(z0, att_c.x, fmaf(z1, att_c.y, fmaf(z2, att_c.z, z3 * att_c.w)));
        #pragma unroll
        for (int off = HEADL / 2; off > 0; off >>= 1)
            p += __shfl_xor(p, off, 64);
        float ex = __expf(fminf(p, 80.f));
        den = ex;
        acc.x = ex * xs4.x; acc.y = ex * xs4.y; acc.z = ex * xs4.z; acc.w = ex * xs4.w;
    }

    // wave-wide max degree (all lanes active; loop is wave-uniform)
    int mdg = dg;
    #pragma unroll
    for (int off = 32; off > 0; off >>= 1) mdg = max(mdg, __shfl_xor(mdg, off, 64));

    float4 cur = xl4[(size_t)col[start] * V4 + c4];   // 0 if empty row (win zeroed)
    for (int k = 0; k < mdg; ++k) {
        float4 x4 = cur;
        if (k + 1 < mdg) {
            int kk = min(k + 1, dg - 1);
            if (kk < 0) kk = 0;
            int sn = col[start + kk];
            cur = xl4[(size_t)sn * V4 + c4];          // in flight during math below
        }
        float z0 = x4.x + xr_c.x; z0 = (z0 >= 0.f) ? z0 : NEG_SLOPE * z0;
        float z1 = x4.y + xr_c.y; z1 = (z1 >= 0.f) ? z1 : NEG_SLOPE * z1;
        float z2 = x4.z + xr_c.z; z2 = (z2 >= 0.f) ? z2 : NEG_SLOPE * z2;
        float z3 = x4.w + xr_c.w; z3 = (z3 >= 0.f) ? z3 : NEG_SLOPE * z3;
        float p = fmaf(z0, att_c.x, fmaf(z1, att_c.y, fmaf(z2, att_c.z, z3 * att_c.w)));
        #pragma unroll
        for (int off = HEADL / 2; off > 0; off >>= 1)
            p += __shfl_xor(p, off, 64);
        float ex = (k < dg) ? __expf(fminf(p, 80.f)) : 0.f;
        den += ex;
        acc.x = fmaf(ex, x4.x, acc.x);
        acc.y = fmaf(ex, x4.y, acc.y);
        acc.z = fmaf(ex, x4.z, acc.z);
        acc.w = fmaf(ex, x4.w, acc.w);
    }
    if (nvalid) {
        float inv = 1.f / den;
        float4 o;
        o.x = fmaf(acc.x, inv, b_c.x); o.x = (o.x > 0.f) ? o.x : (__expf(o.x) - 1.f);
        o.y = fmaf(acc.y, inv, b_c.y); o.y = (o.y > 0.f) ? o.y : (__expf(o.y) - 1.f);
        o.z = fmaf(acc.z, inv, b_c.z); o.z = (o.z > 0.f) ? o.z : (__expf(o.z) - 1.f);
        o.w = fmaf(acc.w, inv, b_c.w); o.w = (o.w > 0.f) ? o.w : (__expf(o.w) - 1.f);
        ((float4*)out)[(size_t)n * V4 + c4] = o;
    }
}

// ---------------- pool + head ----------------
// batch is sorted: accumulate runs locally, one atomic per run boundary.
__global__ void pool_k(const float* __restrict__ h2, const int* __restrict__ batch,
                       float* __restrict__ gsum, float* __restrict__ gcnt) {
    const int NCH = (N_NODES + 7) / 8;
    int t = blockIdx.x * blockDim.x + threadIdx.x;
    if (t >= NCH * 32) return;
    int c = t & 31;
    int n0 = (t >> 5) * 8;
    int nend = min(n0 + 8, N_NODES);
    int curb = batch[n0];
    float s = 0.f, cnt = 0.f;
    for (int n = n0; n < nend; ++n) {
        int bb = batch[n];
        if (bb != curb) {
            atomicAdd(gsum + (size_t)curb * 32 + c, s);
            if (c == 0) atomicAdd(gcnt + curb, cnt);
            s = 0.f; cnt = 0.f; curb = bb;
        }
        s += h2[(size_t)n * 32 + c];
        cnt += 1.f;
    }
    atomicAdd(gsum + (size_t)curb * 32 + c, s);
    if (c == 0) atomicAdd(gcnt + curb, cnt);
}

__global__ void head_k(const float* __restrict__ gsum, const float* __restrict__ gcnt,
                       const float* __restrict__ Wfc, const float* __restrict__ bfc,
                       float* __restrict__ out) {
    int gph = blockIdx.x * blockDim.x + threadIdx.x;
    if (gph >= NUM_GRAPHS) return;
    float inv = 1.f / fmaxf(gcnt[gph], 1.f);
    float logits[6];
    #pragma unroll
    for (int j = 0; j < 6; ++j) logits[j] = bfc[j];
    for (int k = 0; k < 32; ++k) {
        float p = gsum[(size_t)gph * 32 + k] * inv;
        #pragma unroll
        for (int j = 0; j < 6; ++j) logits[j] = fmaf(p, Wfc[k * 6 + j], logits[j]);
    }
    float m = logits[0];
    #pragma unroll
    for (int j = 1; j < 6; ++j) m = fmaxf(m, logits[j]);
    float ssum = 0.f;
    #pragma unroll
    for (int j = 0; j < 6; ++j) ssum += expf(logits[j] - m);
    float lse = m + logf(ssum);
    #pragma unroll
    for (int j = 0; j < 6; ++j) out[(size_t)gph * 6 + j] = logits[j] - lse;
}

extern "C" void kernel_launch(void* const* d_in, const int* in_sizes, int n_in,
                              void* d_out, int out_size, void* d_ws, size_t ws_size,
                              hipStream_t stream) {
    const float* x    = (const float*)d_in[0];
    const int*   ei   = (const int*)d_in[1];   // [2, N_EDGES]: row0 = src, row1 = dst
    const int*   batch= (const int*)d_in[2];
    const float* Wl1  = (const float*)d_in[3];
    const float* bl1  = (const float*)d_in[4];
    const float* Wr1  = (const float*)d_in[5];
    const float* att1 = (const float*)d_in[6];
    const float* b1   = (const float*)d_in[7];
    const float* Wl2  = (const float*)d_in[8];
    const float* bl2  = (const float*)d_in[9];
    const float* Wr2  = (const float*)d_in[10];
    const float* att2 = (const float*)d_in[11];
    const float* b2   = (const float*)d_in[12];
    const float* Wfc  = (const float*)d_in[13];
    const float* bfc  = (const float*)d_in[14];
    float* out = (float*)d_out;

    // ---- workspace layout ----
    char* wsp = (char*)d_ws;
    float* xl1  = (float*)wsp; wsp += (size_t)N_NODES * 64 * 4;
    float* xr1  = (float*)wsp; wsp += (size_t)N_NODES * 64 * 4;
    float* h1   = (float*)wsp; wsp += (size_t)N_NODES * 64 * 4;
    float* xl2  = (float*)wsp; wsp += (size_t)N_NODES * 32 * 4;
    float* xr2  = (float*)wsp; wsp += (size_t)N_NODES * 32 * 4;
    float* h2   = (float*)wsp; wsp += (size_t)N_NODES * 32 * 4;
    float* gsum = (float*)wsp; wsp += (size_t)NUM_GRAPHS * 32 * 4;   // gsum+gcnt adjacent
    float* gcnt = (float*)wsp; wsp += (size_t)NUM_GRAPHS * 4;
    int* col    = (int*)wsp; wsp += ((size_t)N_NODES << LOG_MD) * 4; // 12.8 MB padded CSR
    int* bucket_cnt = (int*)wsp; wsp += NBKT * 4;
    int* bucket_off = (int*)wsp; wsp += NBKT * 4;
    int* bucket_cur = (int*)wsp; wsp += NBKT * 4;
    int2* binned = (int2*)h1;   // alias: dead before conv1 writes h1

    const int TB = 256;

    // ---- binned CSR build ----
    hipMemsetAsync(bucket_cnt, 0, NBKT * sizeof(int), stream);
    hist_k<<<NPART, 256, 0, stream>>>(ei + N_EDGES, bucket_cnt, gsum);
    bscan_k<<<1, 256, 0, stream>>>(bucket_cnt, bucket_off, bucket_cur);
    part_k<<<NPART, 256, 0, stream>>>(ei, bucket_cur, binned);
    build_k<<<NBKT, 256, 0, stream>>>(bucket_off, binned, col);

    // ---- layer 1 ----
    node_linear_dual_k<128, 64, 8, 32><<<(N_NODES + 31) / 32, 256, 0, stream>>>(
        x, Wl1, bl1, Wr1, xl1, xr1);
    {   // 16 lanes/node -> 4 nodes/wave
        int waves = (N_NODES + 3) / 4;
        gat_conv_k<64, 16, 8><<<(waves + 3) / 4, 256, 0, stream>>>(
            col, (const float4*)xl1, (const float4*)xr1, att1, b1, h1);
    }

    // ---- layer 2 ----
    node_linear_split_k<64, 32, 16, 64><<<(N_NODES + 63) / 64, 256, 0, stream>>>(
        h1, Wl2, bl2, Wr2, xl2, xr2);
    {   // 8 lanes/node -> 8 nodes/wave
        int waves = (N_NODES + 7) / 8;
        gat_conv_k<32, 8, 4><<<(waves + 3) / 4, 256, 0, stream>>>(
            col, (const float4*)xl2, (const float4*)xr2, att2, b2, h2);
    }

    // ---- pool + head (gsum/gcnt zeroed inside hist_k) ----
    pool_k<<<(((N_NODES + 7) / 8) * 32 + TB - 1) / TB, TB, 0, stream>>>(h2, batch, gsum, gcnt);
    head_k<<<(NUM_GRAPHS + TB - 1) / TB, TB, 0, stream>>>(gsum, gcnt, Wfc, bfc, out);
}

// Round 10
// 250.888 us; speedup vs baseline: 1.1427x; 1.0714x over previous
//
#include <hip/hip_runtime.h>
#include <math.h>

#define N_NODES 50000
#define N_EDGES 800000
#define NUM_GRAPHS 512
#define NEG_SLOPE 0.2f
#define LOG_MD 6
#define ROWCAP 63          // slots 0..62 = real edges; slot 63 = real-edge count
#define NBKT 196           // ceil(50000/256) buckets of 256 dst nodes
#define NPART 200
#define EPB_PART 4000      // NPART * EPB_PART == N_EDGES

typedef unsigned short ushort_t;
typedef unsigned int   uint_t;
typedef __attribute__((ext_vector_type(4))) float f32x4;
typedef __attribute__((ext_vector_type(8))) short s16x8;

// fp32 -> bf16 with round-to-nearest-even
__device__ __forceinline__ ushort_t f2bf(float f) {
    union { float f; uint_t u; } v; v.f = f;
    uint_t u = v.u;
    return (ushort_t)((u + 0x7fffu + ((u >> 16) & 1u)) >> 16);
}

// ---------------- stage 1: per-bucket histogram (+ zero gsum/gcnt) ----------------
__global__ void hist_k(const int* __restrict__ ei_dst, int* __restrict__ bucket_cnt,
                       float* __restrict__ gz) {
    __shared__ int h[NBKT];
    const int tid = threadIdx.x;
    for (int i = tid; i < NBKT; i += 256) h[i] = 0;
    int gt = blockIdx.x * 256 + tid;                  // 51200 threads cover 16896
    if (gt < NUM_GRAPHS * 33) gz[gt] = 0.f;           // gsum (512*32) + gcnt (512)
    __syncthreads();
    const int base = blockIdx.x * EPB_PART;
    for (int i = tid; i < EPB_PART; i += 256)
        atomicAdd(&h[ei_dst[base + i] >> 8], 1);
    __syncthreads();
    for (int i = tid; i < NBKT; i += 256)
        if (h[i]) atomicAdd(&bucket_cnt[i], h[i]);
}

// ---------------- stage 2: scan bucket counts ----------------
__global__ void bscan_k(const int* __restrict__ bucket_cnt,
                        int* __restrict__ bucket_off, int* __restrict__ bucket_cur) {
    __shared__ int s[256];
    int tid = threadIdx.x;
    s[tid] = (tid < NBKT) ? bucket_cnt[tid] : 0;
    __syncthreads();
    for (int off = 1; off < 256; off <<= 1) {
        int v = (tid >= off) ? s[tid - off] : 0;
        __syncthreads();
        s[tid] += v;
        __syncthreads();
    }
    if (tid < NBKT) {
        int excl = (tid == 0) ? 0 : s[tid - 1];
        bucket_off[tid] = excl;
        bucket_cur[tid] = excl;
    }
}

// ---------------- stage 3: partition edges into bucket-grouped runs ----------------
__global__ void __launch_bounds__(256) part_k(const int* __restrict__ ei,
                                              int* __restrict__ bucket_cur,
                                              int2* __restrict__ binned) {
    __shared__ int2 ebuf[EPB_PART];   // 32 KB
    __shared__ int2 sbuf[EPB_PART];   // 32 KB
    __shared__ int hist[NBKT], loff[NBKT], rk[NBKT], gbase[NBKT];
    __shared__ int s2[256];
    const int tid = threadIdx.x;
    for (int i = tid; i < NBKT; i += 256) { hist[i] = 0; rk[i] = 0; }
    __syncthreads();
    const int base = blockIdx.x * EPB_PART;
    for (int i = tid; i < EPB_PART; i += 256) {
        int s = ei[base + i];
        int d = ei[N_EDGES + base + i];
        ebuf[i] = make_int2(s, d);
        atomicAdd(&hist[d >> 8], 1);
    }
    __syncthreads();
    s2[tid] = (tid < NBKT) ? hist[tid] : 0;
    __syncthreads();
    for (int off = 1; off < 256; off <<= 1) {
        int v = (tid >= off) ? s2[tid - off] : 0;
        __syncthreads();
        s2[tid] += v;
        __syncthreads();
    }
    if (tid < NBKT) {
        loff[tid] = (tid == 0) ? 0 : s2[tid - 1];
        gbase[tid] = hist[tid] ? atomicAdd(&bucket_cur[tid], hist[tid]) : 0;
    }
    __syncthreads();
    for (int i = tid; i < EPB_PART; i += 256) {
        int2 e = ebuf[i];
        int b = e.y >> 8;
        int r = atomicAdd(&rk[b], 1);
        sbuf[loff[b] + r] = e;
    }
    __syncthreads();
    for (int i = tid; i < EPB_PART; i += 256) {
        int2 e = sbuf[i];
        int b = e.y >> 8;
        binned[gbase[b] + (i - loff[b])] = e;
    }
}

// ---------------- stage 4: build padded CSR rows in LDS, write coalesced ----------------
__global__ void __launch_bounds__(256) build_k(const int* __restrict__ bucket_off,
                                               const int2* __restrict__ binned,
                                               int* __restrict__ col) {
    __shared__ int win[256 * ROWCAP];   // 63 KB
    __shared__ int cnt[256];
    const int tid = threadIdx.x;
    for (int i = tid; i < 256 * ROWCAP; i += 256) win[i] = 0;
    if (tid < 256) cnt[tid] = 0;
    __syncthreads();
    const int b = blockIdx.x;
    const int beg = bucket_off[b];
    const int end = (b == NBKT - 1) ? N_EDGES : bucket_off[b + 1];
    for (int i = beg + tid; i < end; i += 256) {
        int2 e = binned[i];
        int row = e.y & 255;
        int c = atomicAdd(&cnt[row], 1);
        if (c < ROWCAP) win[row * ROWCAP + c] = e.x;
    }
    __syncthreads();
    const int n0 = b << 8;
    const int nrows = min(256, N_NODES - n0);
    int* dst = col + ((size_t)n0 << LOG_MD);
    for (int i = tid; i < nrows * 64; i += 256) {
        int row = i >> 6, s = i & 63;
        dst[i] = (s == 63) ? min(cnt[row], ROWCAP) : win[row * ROWCAP + s];
    }
}

// ---------------- layer-1 linear via MFMA bf16 ----------------
// Bt[j][k] = bf16( j<64 ? Wl[k][j] : Wr[k][j-64] ), N x K row-major so B-frags
// are 16B-contiguous ds_read_b128.
__global__ void prep_bt_k(const float* __restrict__ Wl, const float* __restrict__ Wr,
                          ushort_t* __restrict__ Bt) {
    int gid = blockIdx.x * 256 + threadIdx.x;   // 64 blocks x 256 = 16384
    int j = gid >> 7, k = gid & 127;
    float v = (j < 64) ? Wl[k * 64 + j] : Wr[k * 64 + (j - 64)];
    Bt[j * 128 + k] = f2bf(v);
}

// C[50000x128] = x[50000x128] @ B[128x128] via mfma_f32_16x16x32_bf16.
// Block = 4 waves; wave = 16 nodes x 128 cols (8 accum tiles). Bt staged in LDS
// with 272B row stride (16B aligned, 2-way bank conflict = free).
// Frag maps (m89/m120-verified): A[m=lane&15][k=quad*8+j]; B-frag lane holds
// col n=lane&15, k=quad*8+j (contiguous in Bt row). D: col=lane&15,
// row=quad*4+reg.
__global__ void __launch_bounds__(256) linear1_mfma_k(
        const float* __restrict__ x, const ushort_t* __restrict__ Bt,
        const float* __restrict__ bl,
        float* __restrict__ xl, float* __restrict__ xr) {
    __shared__ ushort_t bts[128 * 136];   // 34 KB, stride 136 bf16 = 272 B
    const int tid = threadIdx.x;
    {
        const uint_t* src = (const uint_t*)Bt;
        uint_t* dst = (uint_t*)bts;
        for (int i = tid; i < 8192; i += 256) {
            int row = i >> 6, pos = i & 63;
            dst[row * 68 + pos] = src[i];
        }
    }
    __syncthreads();
    const int lane = tid & 63;
    const int wv = tid >> 6;
    const int q = lane >> 4, m = lane & 15;
    const int n0w = blockIdx.x * 64 + wv * 16;
    const int rowA = min(n0w + m, N_NODES - 1);
    const float* xrow = x + (size_t)rowA * 128;

    f32x4 acc[8];
    #pragma unroll
    for (int t = 0; t < 8; ++t) acc[t] = (f32x4){0.f, 0.f, 0.f, 0.f};

    #pragma unroll
    for (int ks = 0; ks < 4; ++ks) {
        const int k0 = ks * 32 + q * 8;
        float4 a0 = *(const float4*)(xrow + k0);
        float4 a1 = *(const float4*)(xrow + k0 + 4);
        s16x8 af;
        af[0] = (short)f2bf(a0.x); af[1] = (short)f2bf(a0.y);
        af[2] = (short)f2bf(a0.z); af[3] = (short)f2bf(a0.w);
        af[4] = (short)f2bf(a1.x); af[5] = (short)f2bf(a1.y);
        af[6] = (short)f2bf(a1.z); af[7] = (short)f2bf(a1.w);
        #pragma unroll
        for (int t = 0; t < 8; ++t) {
            const s16x8 bf = *(const s16x8*)(bts + (t * 16 + m) * 136 + k0);
            acc[t] = __builtin_amdgcn_mfma_f32_16x16x32_bf16(af, bf, acc[t], 0, 0, 0);
        }
    }
    #pragma unroll
    for (int t = 0; t < 8; ++t) {
        int j = t * 16 + m;
        float bias = (t < 4) ? bl[j] : 0.f;
        #pragma unroll
        for (int r = 0; r < 4; ++r) {
            int n = n0w + q * 4 + r;
            if (n < N_NODES) {
                if (t < 4) xl[(size_t)n * 64 + j] = acc[t][r] + bias;
                else       xr[(size_t)n * 64 + (j - 64)] = acc[t][r];
            }
        }
    }
}

// ---------------- layer-2 tiled node linear (R8-proven fp32 version) ----------------
template<int FIN, int FOUT, int NPB, int KC>
__global__ void __launch_bounds__(256) node_linear2_k(
        const float* __restrict__ x,
        const float* __restrict__ Wl, const float* __restrict__ bl,
        const float* __restrict__ Wr,
        float* __restrict__ xl, float* __restrict__ xr) {
    const int GROUPS = 256 / FOUT;
    const int NPG = NPB / GROUPS;
    __shared__ float xs[NPB * FIN];
    __shared__ float wls[KC * FOUT];
    __shared__ float wrs[KC * FOUT];
    const int tid = threadIdx.x;
    const int n0_blk = blockIdx.x * NPB;
    const int nodes_here = min(NPB, N_NODES - n0_blk);

    const float4* xv = (const float4*)(x + (size_t)n0_blk * FIN);
    const int total4 = nodes_here * FIN / 4;
    for (int i = tid; i < total4; i += 256) ((float4*)xs)[i] = xv[i];

    const int j = tid % FOUT;
    const int g = tid / FOUT;
    float al[NPG], ar[NPG];
    const float blj = bl[j];
    #pragma unroll
    for (int i = 0; i < NPG; ++i) { al[i] = blj; ar[i] = 0.f; }

    const float* xbase = xs + (size_t)g * NPG * FIN;
    for (int kc = 0; kc < FIN; kc += KC) {
        __syncthreads();
        const int CH4 = KC * FOUT / 4;
        const float4* wl4p = (const float4*)(Wl + (size_t)kc * FOUT);
        const float4* wr4p = (const float4*)(Wr + (size_t)kc * FOUT);
        for (int i = tid; i < CH4; i += 256) {
            ((float4*)wls)[i] = wl4p[i];
            ((float4*)wrs)[i] = wr4p[i];
        }
        __syncthreads();
        for (int k = 0; k < KC; k += 4) {
            float wl0 = wls[(k + 0) * FOUT + j], wl1 = wls[(k + 1) * FOUT + j];
            float wl2 = wls[(k + 2) * FOUT + j], wl3 = wls[(k + 3) * FOUT + j];
            float wr0 = wrs[(k + 0) * FOUT + j], wr1 = wrs[(k + 1) * FOUT + j];
            float wr2 = wrs[(k + 2) * FOUT + j], wr3 = wrs[(k + 3) * FOUT + j];
            #pragma unroll
            for (int i = 0; i < NPG; ++i) {
                float4 v = *(const float4*)(xbase + i * FIN + kc + k);
                al[i] = fmaf(v.x, wl0, fmaf(v.y, wl1, fmaf(v.z, wl2, fmaf(v.w, wl3, al[i]))));
                ar[i] = fmaf(v.x, wr0, fmaf(v.y, wr1, fmaf(v.z, wr2, fmaf(v.w, wr3, ar[i]))));
            }
        }
    }
    const int nbase = n0_blk + g * NPG;
    #pragma unroll
    for (int i = 0; i < NPG; ++i) {
        int n = nbase + i;
        if (n < N_NODES) {
            xl[(size_t)n * FOUT + j] = al[i];
            xr[(size_t)n * FOUT + j] = ar[i];
        }
    }
}

// ---------------- fused GATv2 conv, float4 channels, padded CSR ----------------
template<int C2, int LPN, int HEADL>   // channels, lanes/node = C2/4, lanes/head = LPN/2
__global__ void gat_conv_k(const int* __restrict__ col,
                           const float4* __restrict__ xl4, const float4* __restrict__ xr4,
                           const float* __restrict__ att, const float* __restrict__ b,
                           float* __restrict__ out) {
    const int NPW = 64 / LPN;
    const int V4  = C2 / 4;
    int wave = (blockIdx.x * blockDim.x + threadIdx.x) >> 6;
    int lane = threadIdx.x & 63;
    int slot = lane / LPN;
    int c4   = lane % LPN;
    int n = wave * NPW + slot;
    const bool nvalid = (n < N_NODES);
    const int nn = nvalid ? n : (N_NODES - 1);

    const float4 xr_c  = xr4[(size_t)nn * V4 + c4];
    const float4 att_c = ((const float4*)att)[c4];
    const float4 b_c   = ((const float4*)b)[c4];

    const int start = nn << LOG_MD;
    const int dg    = nvalid ? min(col[start + 63], ROWCAP) : 0;

    float4 xs4 = xl4[(size_t)nn * V4 + c4];
    float den;
    float4 acc;
    {
        float z0 = xs4.x + xr_c.x; z0 = (z0 >= 0.f) ? z0 : NEG_SLOPE * z0;
        float z1 = xs4.y + xr_c.y; z1 = (z1 >= 0.f) ? z1 : NEG_SLOPE * z1;
        float z2 = xs4.z + xr_c.z; z2 = (z2 >= 0.f) ? z2 : NEG_SLOPE * z2;
        float z3 = xs4.w + xr_c.w; z3 = (z3 >= 0.f) ? z3 : NEG_SLOPE * z3;
        float p = fmaf(z0, att_c.x, fmaf(z1, att_c.y, fmaf(z2, att_c.z, z3 * att_c.w)));
        #pragma unroll
        for (int off = HEADL / 2; off > 0; off >>= 1)
            p += __shfl_xor(p, off, 64);
        float ex = __expf(fminf(p, 80.f));
        den = ex;
        acc.x = ex * xs4.x; acc.y = ex * xs4.y; acc.z = ex * xs4.z; acc.w = ex * xs4.w;
    }

    int mdg = dg;
    #pragma unroll
    for (int off = 32; off > 0; off >>= 1) mdg = max(mdg, __shfl_xor(mdg, off, 64));

    float4 cur = xl4[(size_t)col[start] * V4 + c4];
    for (int k = 0; k < mdg; ++k) {
        float4 x4 = cur;
        if (k + 1 < mdg) {
            int kk = min(k + 1, dg - 1);
            if (kk < 0) kk = 0;
            int sn = col[start + kk];
            cur = xl4[(size_t)sn * V4 + c4];
        }
        float z0 = x4.x + xr_c.x; z0 = (z0 >= 0.f) ? z0 : NEG_SLOPE * z0;
        float z1 = x4.y + xr_c.y; z1 = (z1 >= 0.f) ? z1 : NEG_SLOPE * z1;
        float z2 = x4.z + xr_c.z; z2 = (z2 >= 0.f) ? z2 : NEG_SLOPE * z2;
        float z3 = x4.w + xr_c.w; z3 = (z3 >= 0.f) ? z3 : NEG_SLOPE * z3;
        float p = fmaf(z0, att_c.x, fmaf(z1, att_c.y, fmaf(z2, att_c.z, z3 * att_c.w)));
        #pragma unroll
        for (int off = HEADL / 2; off > 0; off >>= 1)
            p += __shfl_xor(p, off, 64);
        float ex = (k < dg) ? __expf(fminf(p, 80.f)) : 0.f;
        den += ex;
        acc.x = fmaf(ex, x4.x, acc.x);
        acc.y = fmaf(ex, x4.y, acc.y);
        acc.z = fmaf(ex, x4.z, acc.z);
        acc.w = fmaf(ex, x4.w, acc.w);
    }
    if (nvalid) {
        float inv = 1.f / den;
        float4 o;
        o.x = fmaf(acc.x, inv, b_c.x); o.x = (o.x > 0.f) ? o.x : (__expf(o.x) - 1.f);
        o.y = fmaf(acc.y, inv, b_c.y); o.y = (o.y > 0.f) ? o.y : (__expf(o.y) - 1.f);
        o.z = fmaf(acc.z, inv, b_c.z); o.z = (o.z > 0.f) ? o.z : (__expf(o.z) - 1.f);
        o.w = fmaf(acc.w, inv, b_c.w); o.w = (o.w > 0.f) ? o.w : (__expf(o.w) - 1.f);
        ((float4*)out)[(size_t)n * V4 + c4] = o;
    }
}

// ---------------- pool + head ----------------
__global__ void pool_k(const float* __restrict__ h2, const int* __restrict__ batch,
                       float* __restrict__ gsum, float* __restrict__ gcnt) {
    const int NCH = (N_NODES + 7) / 8;
    int t = blockIdx.x * blockDim.x + threadIdx.x;
    if (t >= NCH * 32) return;
    int c = t & 31;
    int n0 = (t >> 5) * 8;
    int nend = min(n0 + 8, N_NODES);
    int curb = batch[n0];
    float s = 0.f, cnt = 0.f;
    for (int n = n0; n < nend; ++n) {
        int bb = batch[n];
        if (bb != curb) {
            atomicAdd(gsum + (size_t)curb * 32 + c, s);
            if (c == 0) atomicAdd(gcnt + curb, cnt);
            s = 0.f; cnt = 0.f; curb = bb;
        }
        s += h2[(size_t)n * 32 + c];
        cnt += 1.f;
    }
    atomicAdd(gsum + (size_t)curb * 32 + c, s);
    if (c == 0) atomicAdd(gcnt + curb, cnt);
}

__global__ void head_k(const float* __restrict__ gsum, const float* __restrict__ gcnt,
                       const float* __restrict__ Wfc, const float* __restrict__ bfc,
                       float* __restrict__ out) {
    int gph = blockIdx.x * blockDim.x + threadIdx.x;
    if (gph >= NUM_GRAPHS) return;
    float inv = 1.f / fmaxf(gcnt[gph], 1.f);
    float logits[6];
    #pragma unroll
    for (int j = 0; j < 6; ++j) logits[j] = bfc[j];
    for (int k = 0; k < 32; ++k) {
        float p = gsum[(size_t)gph * 32 + k] * inv;
        #pragma unroll
        for (int j = 0; j < 6; ++j) logits[j] = fmaf(p, Wfc[k * 6 + j], logits[j]);
    }
    float m = logits[0];
    #pragma unroll
    for (int j = 1; j < 6; ++j) m = fmaxf(m, logits[j]);
    float ssum = 0.f;
    #pragma unroll
    for (int j = 0; j < 6; ++j) ssum += expf(logits[j] - m);
    float lse = m + logf(ssum);
    #pragma unroll
    for (int j = 0; j < 6; ++j) out[(size_t)gph * 6 + j] = logits[j] - lse;
}

extern "C" void kernel_launch(void* const* d_in, const int* in_sizes, int n_in,
                              void* d_out, int out_size, void* d_ws, size_t ws_size,
                              hipStream_t stream) {
    const float* x    = (const float*)d_in[0];
    const int*   ei   = (const int*)d_in[1];
    const int*   batch= (const int*)d_in[2];
    const float* Wl1  = (const float*)d_in[3];
    const float* bl1  = (const float*)d_in[4];
    const float* Wr1  = (const float*)d_in[5];
    const float* att1 = (const float*)d_in[6];
    const float* b1   = (const float*)d_in[7];
    const float* Wl2  = (const float*)d_in[8];
    const float* bl2  = (const float*)d_in[9];
    const float* Wr2  = (const float*)d_in[10];
    const float* att2 = (const float*)d_in[11];
    const float* b2   = (const float*)d_in[12];
    const float* Wfc  = (const float*)d_in[13];
    const float* bfc  = (const float*)d_in[14];
    float* out = (float*)d_out;

    // ---- workspace layout ----
    char* wsp = (char*)d_ws;
    float* xl1  = (float*)wsp; wsp += (size_t)N_NODES * 64 * 4;
    float* xr1  = (float*)wsp; wsp += (size_t)N_NODES * 64 * 4;
    float* h1   = (float*)wsp; wsp += (size_t)N_NODES * 64 * 4;
    float* xl2  = (float*)wsp; wsp += (size_t)N_NODES * 32 * 4;
    float* xr2  = (float*)wsp; wsp += (size_t)N_NODES * 32 * 4;
    float* h2   = (float*)wsp; wsp += (size_t)N_NODES * 32 * 4;
    float* gsum = (float*)wsp; wsp += (size_t)NUM_GRAPHS * 32 * 4;
    float* gcnt = (float*)wsp; wsp += (size_t)NUM_GRAPHS * 4;
    int* col    = (int*)wsp; wsp += ((size_t)N_NODES << LOG_MD) * 4;
    int* bucket_cnt = (int*)wsp; wsp += NBKT * 4;
    int* bucket_off = (int*)wsp; wsp += NBKT * 4;
    int* bucket_cur = (int*)wsp; wsp += NBKT * 4;
    ushort_t* Bt = (ushort_t*)wsp; wsp += 128 * 128 * 2;   // bf16 [Wl|Wr]^T
    int2* binned = (int2*)h1;   // alias: dead before conv1 writes h1

    const int TB = 256;

    // ---- binned CSR build + weight prep ----
    hipMemsetAsync(bucket_cnt, 0, NBKT * sizeof(int), stream);
    prep_bt_k<<<64, 256, 0, stream>>>(Wl1, Wr1, Bt);
    hist_k<<<NPART, 256, 0, stream>>>(ei + N_EDGES, bucket_cnt, gsum);
    bscan_k<<<1, 256, 0, stream>>>(bucket_cnt, bucket_off, bucket_cur);
    part_k<<<NPART, 256, 0, stream>>>(ei, bucket_cur, binned);
    build_k<<<NBKT, 256, 0, stream>>>(bucket_off, binned, col);

    // ---- layer 1 (MFMA bf16 GEMM) ----
    linear1_mfma_k<<<(N_NODES + 63) / 64, 256, 0, stream>>>(x, Bt, bl1, xl1, xr1);
    {   // 16 lanes/node -> 4 nodes/wave
        int waves = (N_NODES + 3) / 4;
        gat_conv_k<64, 16, 8><<<(waves + 3) / 4, 256, 0, stream>>>(
            col, (const float4*)xl1, (const float4*)xr1, att1, b1, h1);
    }

    // ---- layer 2 ----
    node_linear2_k<64, 32, 64, 32><<<(N_NODES + 63) / 64, 256, 0, stream>>>(
        h1, Wl2, bl2, Wr2, xl2, xr2);
    {   // 8 lanes/node -> 8 nodes/wave
        int waves = (N_NODES + 7) / 8;
        gat_conv_k<32, 8, 4><<<(waves + 3) / 4, 256, 0, stream>>>(
            col, (const float4*)xl2, (const float4*)xr2, att2, b2, h2);
    }

    // ---- pool + head (gsum/gcnt zeroed inside hist_k) ----
    pool_k<<<(((N_NODES + 7) / 8) * 32 + TB - 1) / TB, TB, 0, stream>>>(h2, batch, gsum, gcnt);
    head_k<<<(NUM_GRAPHS + TB - 1) / TB, TB, 0, stream>>>(gsum, gcnt, Wfc, bfc, out);
}

// Round 11
// 217.430 us; speedup vs baseline: 1.3185x; 1.1539x over previous
//
#include <hip/hip_runtime.h>
#include <math.h>

#define N_NODES 50000
#define N_EDGES 800000
#define NUM_GRAPHS 512
#define NEG_SLOPE 0.2f
#define LOG_MD 6
#define ROWCAP 63          // slots 0..62 = real edges; slot 63 = real-edge count
#define NBKT 196           // ceil(50000/256) buckets of 256 dst nodes
#define NPART 200
#define EPB_PART 4000      // NPART * EPB_PART == N_EDGES

typedef unsigned short ushort_t;
typedef unsigned int   uint_t;
typedef __attribute__((ext_vector_type(4))) float f32x4;
typedef __attribute__((ext_vector_type(8))) short s16x8;

// fp32 -> bf16 with round-to-nearest-even
__device__ __forceinline__ ushort_t f2bf(float f) {
    union { float f; uint_t u; } v; v.f = f;
    uint_t u = v.u;
    return (ushort_t)((u + 0x7fffu + ((u >> 16) & 1u)) >> 16);
}

__device__ __forceinline__ void unpack8(const ushort_t* p, float* f) {
    uint4 u = *(const uint4*)p;
    f[0] = __uint_as_float(u.x << 16); f[1] = __uint_as_float(u.x & 0xffff0000u);
    f[2] = __uint_as_float(u.y << 16); f[3] = __uint_as_float(u.y & 0xffff0000u);
    f[4] = __uint_as_float(u.z << 16); f[5] = __uint_as_float(u.z & 0xffff0000u);
    f[6] = __uint_as_float(u.w << 16); f[7] = __uint_as_float(u.w & 0xffff0000u);
}

// ---------------- stage 1: per-bucket histogram (+ zero gsum/gcnt) ----------------
__global__ void hist_k(const int* __restrict__ ei_dst, int* __restrict__ bucket_cnt,
                       float* __restrict__ gz) {
    __shared__ int h[NBKT];
    const int tid = threadIdx.x;
    for (int i = tid; i < NBKT; i += 256) h[i] = 0;
    int gt = blockIdx.x * 256 + tid;
    if (gt < NUM_GRAPHS * 33) gz[gt] = 0.f;           // gsum (512*32) + gcnt (512)
    __syncthreads();
    const int base = blockIdx.x * EPB_PART;
    for (int i = tid; i < EPB_PART; i += 256)
        atomicAdd(&h[ei_dst[base + i] >> 8], 1);
    __syncthreads();
    for (int i = tid; i < NBKT; i += 256)
        if (h[i]) atomicAdd(&bucket_cnt[i], h[i]);
}

// ---------------- stage 2: scan bucket counts ----------------
__global__ void bscan_k(const int* __restrict__ bucket_cnt,
                        int* __restrict__ bucket_off, int* __restrict__ bucket_cur) {
    __shared__ int s[256];
    int tid = threadIdx.x;
    s[tid] = (tid < NBKT) ? bucket_cnt[tid] : 0;
    __syncthreads();
    for (int off = 1; off < 256; off <<= 1) {
        int v = (tid >= off) ? s[tid - off] : 0;
        __syncthreads();
        s[tid] += v;
        __syncthreads();
    }
    if (tid < NBKT) {
        int excl = (tid == 0) ? 0 : s[tid - 1];
        bucket_off[tid] = excl;
        bucket_cur[tid] = excl;
    }
}

// ---------------- stage 3: partition edges into bucket-grouped runs ----------------
__global__ void __launch_bounds__(256) part_k(const int* __restrict__ ei,
                                              int* __restrict__ bucket_cur,
                                              int2* __restrict__ binned) {
    __shared__ int2 ebuf[EPB_PART];   // 32 KB
    __shared__ int2 sbuf[EPB_PART];   // 32 KB
    __shared__ int hist[NBKT], loff[NBKT], rk[NBKT], gbase[NBKT];
    __shared__ int s2[256];
    const int tid = threadIdx.x;
    for (int i = tid; i < NBKT; i += 256) { hist[i] = 0; rk[i] = 0; }
    __syncthreads();
    const int base = blockIdx.x * EPB_PART;
    for (int i = tid; i < EPB_PART; i += 256) {
        int s = ei[base + i];
        int d = ei[N_EDGES + base + i];
        ebuf[i] = make_int2(s, d);
        atomicAdd(&hist[d >> 8], 1);
    }
    __syncthreads();
    s2[tid] = (tid < NBKT) ? hist[tid] : 0;
    __syncthreads();
    for (int off = 1; off < 256; off <<= 1) {
        int v = (tid >= off) ? s2[tid - off] : 0;
        __syncthreads();
        s2[tid] += v;
        __syncthreads();
    }
    if (tid < NBKT) {
        loff[tid] = (tid == 0) ? 0 : s2[tid - 1];
        gbase[tid] = hist[tid] ? atomicAdd(&bucket_cur[tid], hist[tid]) : 0;
    }
    __syncthreads();
    for (int i = tid; i < EPB_PART; i += 256) {
        int2 e = ebuf[i];
        int b = e.y >> 8;
        int r = atomicAdd(&rk[b], 1);
        sbuf[loff[b] + r] = e;
    }
    __syncthreads();
    for (int i = tid; i < EPB_PART; i += 256) {
        int2 e = sbuf[i];
        int b = e.y >> 8;
        binned[gbase[b] + (i - loff[b])] = e;
    }
}

// ---------------- stage 4: build padded CSR rows in LDS, write coalesced ----------------
__global__ void __launch_bounds__(256) build_k(const int* __restrict__ bucket_off,
                                               const int2* __restrict__ binned,
                                               int* __restrict__ col) {
    __shared__ int win[256 * ROWCAP];   // 63 KB
    __shared__ int cnt[256];
    const int tid = threadIdx.x;
    for (int i = tid; i < 256 * ROWCAP; i += 256) win[i] = 0;
    if (tid < 256) cnt[tid] = 0;
    __syncthreads();
    const int b = blockIdx.x;
    const int beg = bucket_off[b];
    const int end = (b == NBKT - 1) ? N_EDGES : bucket_off[b + 1];
    for (int i = beg + tid; i < end; i += 256) {
        int2 e = binned[i];
        int row = e.y & 255;
        int c = atomicAdd(&cnt[row], 1);
        if (c < ROWCAP) win[row * ROWCAP + c] = e.x;
    }
    __syncthreads();
    const int n0 = b << 8;
    const int nrows = min(256, N_NODES - n0);
    int* dst = col + ((size_t)n0 << LOG_MD);
    for (int i = tid; i < nrows * 64; i += 256) {
        int row = i >> 6, s = i & 63;
        dst[i] = (s == 63) ? min(cnt[row], ROWCAP) : win[row * ROWCAP + s];
    }
}

// ---------------- weight prep: Bt1 = bf16 [Wl1|Wr1]^T, Bt2 = bf16 [Wl2|Wr2]^T ----------------
__global__ void prep_bt_k(const float* __restrict__ Wl1, const float* __restrict__ Wr1,
                          const float* __restrict__ Wl2, const float* __restrict__ Wr2,
                          ushort_t* __restrict__ Bt1, ushort_t* __restrict__ Bt2) {
    int gid = blockIdx.x * 256 + threadIdx.x;   // 80 blocks x 256 = 20480
    if (gid < 16384) {
        int j = gid >> 7, k = gid & 127;
        float v = (j < 64) ? Wl1[k * 64 + j] : Wr1[k * 64 + (j - 64)];
        Bt1[gid] = f2bf(v);
    } else if (gid < 16384 + 4096) {
        int g = gid - 16384;
        int j = g >> 6, k = g & 63;
        float v = (j < 32) ? Wl2[k * 32 + j] : Wr2[k * 32 + (j - 32)];
        Bt2[g] = f2bf(v);
    }
}

// ---------------- layer-1 linear: [50000x128] @ [128x128] MFMA bf16, bf16 out ----------------
__global__ void __launch_bounds__(256) linear1_mfma_k(
        const float* __restrict__ x, const ushort_t* __restrict__ Bt,
        const float* __restrict__ bl,
        ushort_t* __restrict__ xl, ushort_t* __restrict__ xr) {
    __shared__ ushort_t bts[128 * 136];   // 34 KB, stride 272 B (2-way conflict = free)
    const int tid = threadIdx.x;
    {
        const uint_t* src = (const uint_t*)Bt;
        uint_t* dst = (uint_t*)bts;
        for (int i = tid; i < 8192; i += 256) {
            int row = i >> 6, pos = i & 63;
            dst[row * 68 + pos] = src[i];
        }
    }
    __syncthreads();
    const int lane = tid & 63;
    const int wv = tid >> 6;
    const int q = lane >> 4, m = lane & 15;
    const int n0w = blockIdx.x * 64 + wv * 16;
    const int rowA = min(n0w + m, N_NODES - 1);
    const float* xrow = x + (size_t)rowA * 128;

    f32x4 acc[8];
    #pragma unroll
    for (int t = 0; t < 8; ++t) acc[t] = (f32x4){0.f, 0.f, 0.f, 0.f};

    #pragma unroll
    for (int ks = 0; ks < 4; ++ks) {
        const int k0 = ks * 32 + q * 8;
        float4 a0 = *(const float4*)(xrow + k0);
        float4 a1 = *(const float4*)(xrow + k0 + 4);
        s16x8 af;
        af[0] = (short)f2bf(a0.x); af[1] = (short)f2bf(a0.y);
        af[2] = (short)f2bf(a0.z); af[3] = (short)f2bf(a0.w);
        af[4] = (short)f2bf(a1.x); af[5] = (short)f2bf(a1.y);
        af[6] = (short)f2bf(a1.z); af[7] = (short)f2bf(a1.w);
        #pragma unroll
        for (int t = 0; t < 8; ++t) {
            const s16x8 bf = *(const s16x8*)(bts + (t * 16 + m) * 136 + k0);
            acc[t] = __builtin_amdgcn_mfma_f32_16x16x32_bf16(af, bf, acc[t], 0, 0, 0);
        }
    }
    #pragma unroll
    for (int t = 0; t < 8; ++t) {
        int j = t * 16 + m;
        float bias = (t < 4) ? bl[j] : 0.f;
        #pragma unroll
        for (int r = 0; r < 4; ++r) {
            int n = n0w + q * 4 + r;
            if (n < N_NODES) {
                if (t < 4) xl[(size_t)n * 64 + j] = f2bf(acc[t][r] + bias);
                else       xr[(size_t)n * 64 + (j - 64)] = f2bf(acc[t][r]);
            }
        }
    }
}

// ---------------- layer-2 linear: [50000x64] @ [64x64] MFMA bf16 (A already bf16) ----------------
__global__ void __launch_bounds__(256) linear2_mfma_k(
        const ushort_t* __restrict__ h1, const ushort_t* __restrict__ Bt2,
        const float* __restrict__ bl2,
        ushort_t* __restrict__ xl2, ushort_t* __restrict__ xr2) {
    __shared__ ushort_t bts[64 * 72];   // 9 KB, stride 144 B
    const int tid = threadIdx.x;
    {
        const uint_t* src = (const uint_t*)Bt2;   // 2048 uints
        uint_t* dst = (uint_t*)bts;
        for (int i = tid; i < 2048; i += 256) {
            int row = i >> 5, pos = i & 31;
            dst[row * 36 + pos] = src[i];
        }
    }
    __syncthreads();
    const int lane = tid & 63;
    const int wv = tid >> 6;
    const int q = lane >> 4, m = lane & 15;
    const int n0w = blockIdx.x * 64 + wv * 16;
    const int rowA = min(n0w + m, N_NODES - 1);
    const ushort_t* hrow = h1 + (size_t)rowA * 64;

    f32x4 acc[4];
    #pragma unroll
    for (int t = 0; t < 4; ++t) acc[t] = (f32x4){0.f, 0.f, 0.f, 0.f};

    #pragma unroll
    for (int ks = 0; ks < 2; ++ks) {
        const int k0 = ks * 32 + q * 8;
        const s16x8 af = *(const s16x8*)(hrow + k0);
        #pragma unroll
        for (int t = 0; t < 4; ++t) {
            const s16x8 bf = *(const s16x8*)(bts + (t * 16 + m) * 72 + k0);
            acc[t] = __builtin_amdgcn_mfma_f32_16x16x32_bf16(af, bf, acc[t], 0, 0, 0);
        }
    }
    #pragma unroll
    for (int t = 0; t < 4; ++t) {
        int j = t * 16 + m;
        float bias = (t < 2) ? bl2[j] : 0.f;
        #pragma unroll
        for (int r = 0; r < 4; ++r) {
            int n = n0w + q * 4 + r;
            if (n < N_NODES) {
                if (t < 2) xl2[(size_t)n * 32 + j] = f2bf(acc[t][r] + bias);
                else       xr2[(size_t)n * 32 + (j - 32)] = f2bf(acc[t][r]);
            }
        }
    }
}

// ---------------- fused GATv2 conv, bf16 gathers, 8 channels/lane ----------------
// LPN = C2/8 lanes/node, NPW = 64/LPN edges per wave-iteration. Head groups are
// HEADL-lane aligned (xor offs < HEADL stay inside). fp32 accumulate/softmax.
template<int C2, int LPN, int HEADL, bool OUT_BF16>
__global__ void __launch_bounds__(256) gat_conv_k(
        const int* __restrict__ col,
        const ushort_t* __restrict__ xl, const ushort_t* __restrict__ xr,
        const float* __restrict__ att, const float* __restrict__ b,
        void* __restrict__ outp) {
    const int NPW = 64 / LPN;
    int wave = (blockIdx.x * blockDim.x + threadIdx.x) >> 6;
    int lane = threadIdx.x & 63;
    int slot = lane / LPN;
    int c8   = lane % LPN;        // 8-channel group
    int n = wave * NPW + slot;
    const bool nvalid = (n < N_NODES);
    const int nn = nvalid ? n : (N_NODES - 1);

    float xrv[8], attv[8], bv[8];
    unpack8(xr + (size_t)nn * C2 + c8 * 8, xrv);
    *(float4*)(attv)     = ((const float4*)att)[c8 * 2];
    *(float4*)(attv + 4) = ((const float4*)att)[c8 * 2 + 1];
    *(float4*)(bv)       = ((const float4*)b)[c8 * 2];
    *(float4*)(bv + 4)   = ((const float4*)b)[c8 * 2 + 1];

    const int start = nn << LOG_MD;
    const int dg = nvalid ? min(col[start + 63], ROWCAP) : 0;

    float den, acc[8];
    {   // self loop (coalesced)
        float xsv[8];
        unpack8(xl + (size_t)nn * C2 + c8 * 8, xsv);
        float p = 0.f;
        #pragma unroll
        for (int i = 0; i < 8; ++i) {
            float z = xsv[i] + xrv[i];
            z = (z >= 0.f) ? z : NEG_SLOPE * z;
            p = fmaf(z, attv[i], p);
        }
        #pragma unroll
        for (int off = HEADL / 2; off > 0; off >>= 1)
            p += __shfl_xor(p, off, 64);
        float ex = __expf(fminf(p, 80.f));
        den = ex;
        #pragma unroll
        for (int i = 0; i < 8; ++i) acc[i] = ex * xsv[i];
    }

    int mdg = dg;
    #pragma unroll
    for (int off = 32; off > 0; off >>= 1) mdg = max(mdg, __shfl_xor(mdg, off, 64));

    uint4 raw = *(const uint4*)(xl + (size_t)col[start] * C2 + c8 * 8);
    for (int k = 0; k < mdg; ++k) {
        uint4 cu = raw;
        if (k + 1 < mdg) {
            int kk = min(k + 1, dg - 1);
            if (kk < 0) kk = 0;
            int sn = col[start + kk];
            raw = *(const uint4*)(xl + (size_t)sn * C2 + c8 * 8);   // in flight
        }
        float xv[8];
        xv[0] = __uint_as_float(cu.x << 16); xv[1] = __uint_as_float(cu.x & 0xffff0000u);
        xv[2] = __uint_as_float(cu.y << 16); xv[3] = __uint_as_float(cu.y & 0xffff0000u);
        xv[4] = __uint_as_float(cu.z << 16); xv[5] = __uint_as_float(cu.z & 0xffff0000u);
        xv[6] = __uint_as_float(cu.w << 16); xv[7] = __uint_as_float(cu.w & 0xffff0000u);
        float p = 0.f;
        #pragma unroll
        for (int i = 0; i < 8; ++i) {
            float z = xv[i] + xrv[i];
            z = (z >= 0.f) ? z : NEG_SLOPE * z;
            p = fmaf(z, attv[i], p);
        }
        #pragma unroll
        for (int off = HEADL / 2; off > 0; off >>= 1)
            p += __shfl_xor(p, off, 64);
        float ex = (k < dg) ? __expf(fminf(p, 80.f)) : 0.f;
        den += ex;
        #pragma unroll
        for (int i = 0; i < 8; ++i) acc[i] = fmaf(ex, xv[i], acc[i]);
    }
    if (nvalid) {
        float inv = 1.f / den;
        float o[8];
        #pragma unroll
        for (int i = 0; i < 8; ++i) {
            float v = fmaf(acc[i], inv, bv[i]);
            o[i] = (v > 0.f) ? v : (__expf(v) - 1.f);
        }
        if (OUT_BF16) {
            uint4 u;
            u.x = ((uint_t)f2bf(o[1]) << 16) | f2bf(o[0]);
            u.y = ((uint_t)f2bf(o[3]) << 16) | f2bf(o[2]);
            u.z = ((uint_t)f2bf(o[5]) << 16) | f2bf(o[4]);
            u.w = ((uint_t)f2bf(o[7]) << 16) | f2bf(o[6]);
            ((uint4*)outp)[(size_t)n * (C2 / 8) + c8] = u;
        } else {
            float4* op = (float4*)outp;
            op[(size_t)n * (C2 / 4) + c8 * 2]     = *(float4*)o;
            op[(size_t)n * (C2 / 4) + c8 * 2 + 1] = *(float4*)(o + 4);
        }
    }
}

// ---------------- pool + head ----------------
__global__ void pool_k(const float* __restrict__ h2, const int* __restrict__ batch,
                       float* __restrict__ gsum, float* __restrict__ gcnt) {
    const int NCH = (N_NODES + 7) / 8;
    int t = blockIdx.x * blockDim.x + threadIdx.x;
    if (t >= NCH * 32) return;
    int c = t & 31;
    int n0 = (t >> 5) * 8;
    int nend = min(n0 + 8, N_NODES);
    int curb = batch[n0];
    float s = 0.f, cnt = 0.f;
    for (int n = n0; n < nend; ++n) {
        int bb = batch[n];
        if (bb != curb) {
            atomicAdd(gsum + (size_t)curb * 32 + c, s);
            if (c == 0) atomicAdd(gcnt + curb, cnt);
            s = 0.f; cnt = 0.f; curb = bb;
        }
        s += h2[(size_t)n * 32 + c];
        cnt += 1.f;
    }
    atomicAdd(gsum + (size_t)curb * 32 + c, s);
    if (c == 0) atomicAdd(gcnt + curb, cnt);
}

__global__ void head_k(const float* __restrict__ gsum, const float* __restrict__ gcnt,
                       const float* __restrict__ Wfc, const float* __restrict__ bfc,
                       float* __restrict__ out) {
    int gph = blockIdx.x * blockDim.x + threadIdx.x;
    if (gph >= NUM_GRAPHS) return;
    float inv = 1.f / fmaxf(gcnt[gph], 1.f);
    float logits[6];
    #pragma unroll
    for (int j = 0; j < 6; ++j) logits[j] = bfc[j];
    for (int k = 0; k < 32; ++k) {
        float p = gsum[(size_t)gph * 32 + k] * inv;
        #pragma unroll
        for (int j = 0; j < 6; ++j) logits[j] = fmaf(p, Wfc[k * 6 + j], logits[j]);
    }
    float m = logits[0];
    #pragma unroll
    for (int j = 1; j < 6; ++j) m = fmaxf(m, logits[j]);
    float ssum = 0.f;
    #pragma unroll
    for (int j = 0; j < 6; ++j) ssum += expf(logits[j] - m);
    float lse = m + logf(ssum);
    #pragma unroll
    for (int j = 0; j < 6; ++j) out[(size_t)gph * 6 + j] = logits[j] - lse;
}

extern "C" void kernel_launch(void* const* d_in, const int* in_sizes, int n_in,
                              void* d_out, int out_size, void* d_ws, size_t ws_size,
                              hipStream_t stream) {
    const float* x    = (const float*)d_in[0];
    const int*   ei   = (const int*)d_in[1];
    const int*   batch= (const int*)d_in[2];
    const float* Wl1  = (const float*)d_in[3];
    const float* bl1  = (const float*)d_in[4];
    const float* Wr1  = (const float*)d_in[5];
    const float* att1 = (const float*)d_in[6];
    const float* b1   = (const float*)d_in[7];
    const float* Wl2  = (const float*)d_in[8];
    const float* bl2  = (const float*)d_in[9];
    const float* Wr2  = (const float*)d_in[10];
    const float* att2 = (const float*)d_in[11];
    const float* b2   = (const float*)d_in[12];
    const float* Wfc  = (const float*)d_in[13];
    const float* bfc  = (const float*)d_in[14];
    float* out = (float*)d_out;

    // ---- workspace layout (all bf16 intermediates except h2) ----
    char* wsp = (char*)d_ws;
    ushort_t* xl1 = (ushort_t*)wsp; wsp += (size_t)N_NODES * 64 * 2;   // 6.4 MB
    ushort_t* xr1 = (ushort_t*)wsp; wsp += (size_t)N_NODES * 64 * 2;
    ushort_t* h1  = (ushort_t*)wsp; wsp += (size_t)N_NODES * 64 * 2;
    ushort_t* xl2 = (ushort_t*)wsp; wsp += (size_t)N_NODES * 32 * 2;   // 3.2 MB
    ushort_t* xr2 = (ushort_t*)wsp; wsp += (size_t)N_NODES * 32 * 2;
    float* h2   = (float*)wsp; wsp += (size_t)N_NODES * 32 * 4;        // fp32 for pool
    float* gsum = (float*)wsp; wsp += (size_t)NUM_GRAPHS * 32 * 4;
    float* gcnt = (float*)wsp; wsp += (size_t)NUM_GRAPHS * 4;
    int* col    = (int*)wsp; wsp += ((size_t)N_NODES << LOG_MD) * 4;   // 12.8 MB
    int* bucket_cnt = (int*)wsp; wsp += NBKT * 4;
    int* bucket_off = (int*)wsp; wsp += NBKT * 4;
    int* bucket_cur = (int*)wsp; wsp += NBKT * 4;
    wsp += 16 - ((size_t)wsp & 15);
    ushort_t* Bt1 = (ushort_t*)wsp; wsp += 128 * 128 * 2;
    ushort_t* Bt2 = (ushort_t*)wsp; wsp += 64 * 64 * 2;
    int2* binned = (int2*)h1;   // alias: h1 (6.4 MB) dead until conv1 writes it

    const int TB = 256;

    // ---- weight prep + binned CSR build ----
    hipMemsetAsync(bucket_cnt, 0, NBKT * sizeof(int), stream);
    prep_bt_k<<<80, 256, 0, stream>>>(Wl1, Wr1, Wl2, Wr2, Bt1, Bt2);
    hist_k<<<NPART, 256, 0, stream>>>(ei + N_EDGES, bucket_cnt, gsum);
    bscan_k<<<1, 256, 0, stream>>>(bucket_cnt, bucket_off, bucket_cur);
    part_k<<<NPART, 256, 0, stream>>>(ei, bucket_cur, binned);
    build_k<<<NBKT, 256, 0, stream>>>(bucket_off, binned, col);

    // ---- layer 1 ----
    linear1_mfma_k<<<(N_NODES + 63) / 64, 256, 0, stream>>>(x, Bt1, bl1, xl1, xr1);
    {   // 8 lanes/node -> 8 nodes/wave
        int waves = (N_NODES + 7) / 8;
        gat_conv_k<64, 8, 4, true><<<(waves + 3) / 4, 256, 0, stream>>>(
            col, xl1, xr1, att1, b1, h1);
    }

    // ---- layer 2 ----
    linear2_mfma_k<<<(N_NODES + 63) / 64, 256, 0, stream>>>(h1, Bt2, bl2, xl2, xr2);
    {   // 4 lanes/node -> 16 nodes/wave
        int waves = (N_NODES + 15) / 16;
        gat_conv_k<32, 4, 2, false><<<(waves + 3) / 4, 256, 0, stream>>>(
            col, xl2, xr2, att2, b2, h2);
    }

    // ---- pool + head (gsum/gcnt zeroed inside hist_k) ----
    pool_k<<<(((N_NODES + 7) / 8) * 32 + TB - 1) / TB, TB, 0, stream>>>(h2, batch, gsum, gcnt);
    head_k<<<(NUM_GRAPHS + TB - 1) / TB, TB, 0, stream>>>(gsum, gcnt, Wfc, bfc, out);
}